// Round 4
// baseline (271.656 us; speedup 1.0000x reference)
//
#include <hip/hip_runtime.h>
#include <hip/hip_bf16.h>

#define BB   32
#define NN   2048
#define DIN  128
#define DOUT 256
#define DCTX 259

// ---- workspace layout (float-slot offsets) ----
#define OFF_AB   0u          // A  bf16 [B][256][256] (dead before kF)
#define OFF_WMB  16777216u   // WM bf16 [B][256 e][128 i] = 524288
#define OFF_WLB  17301504u   // W_layer bf16 [256 o][128 i] = 16384
#define OFF_WLTB 17317888u   // W_layer^T bf16 [128 i][256 o] = 16384
#define OFF_WTCB 17334272u   // W_tc bf16 [256 e][256 o] = 32768
#define OFF_G    17367040u
#define OFF_HB   17375232u
#define OFF_TB   17383424u
#define OFF_P1   17391616u   // BN partial s1 [32 b][2048 n] fp32
#define OFF_P2   17457152u   // BN partial s2 [32 b][2048 n] fp32
// end 17522688 slots ≈ 70.1 MB

typedef short bf16x8 __attribute__((ext_vector_type(8)));
typedef float f32x4  __attribute__((ext_vector_type(4)));

static __device__ inline unsigned short f2bf(float f) {
    __hip_bfloat16 h = __float2bfloat16(f);
    return *(unsigned short*)&h;
}
static __device__ inline float bf2f(unsigned short u) {
    unsigned v = ((unsigned)u) << 16;
    float f;
    __builtin_memcpy(&f, &v, 4);
    return f;
}

// Merged pack + prep. Blocks 0..31: per-b ctx GEMVs (transpose-free, 16-lane row
// dots) + split softmax stats + A bf16. Blocks 32,33: weight packing (independent).
__global__ __launch_bounds__(1024) void kPW(const float* __restrict__ ctx,
                                            const float* __restrict__ bg,
                                            const float* __restrict__ Wl,
                                            const float* __restrict__ Wtc,
                                            const float* __restrict__ Wk,
                                            const float* __restrict__ Wv,
                                            const float* __restrict__ Wg,
                                            const float* __restrict__ Whb,
                                            float* __restrict__ ws) {
    const int bb = blockIdx.x, t = threadIdx.x;
    if (bb >= BB) {
        if (bb == BB) {                      // Wtc -> bf16 [256 e][256 o]
            unsigned short* dst = (unsigned short*)(ws + OFF_WTCB);
            for (int i = t; i < 65536; i += 1024) dst[i] = f2bf(Wtc[i]);
        } else {                             // Wl -> bf16 [o][i] and [i][o]
            unsigned short* d0 = (unsigned short*)(ws + OFF_WLB);
            unsigned short* d1 = (unsigned short*)(ws + OFF_WLTB);
            for (int i = t; i < 32768; i += 1024) {
                float v = Wl[i];
                d0[i] = f2bf(v);
                int o = i >> 7, c = i & 127;
                d1[c * 256 + o] = f2bf(v);
            }
        }
        return;
    }

    const int b = bb;
    const int o = t & 255, q = t >> 8;
    const int wid = t >> 6, l = t & 63;
    __shared__ __align__(16) float cs[260];
    __shared__ __align__(16) float ks[256], vs[256], rms[256], ris[256];
    __shared__ float pm[1024], ps[1024];
    for (int i = t; i < DCTX; i += 1024) cs[i] = ctx[b * DCTX + i];
    __syncthreads();

    // ---- GEMVs straight from row-major W: 16-lane group per dot ----
    {
        const int g16 = l >> 4, lane16 = l & 15;
        const int m = wid >> 2;              // wave-uniform matrix select
        const float* Wm; int C;
        if (m == 0)      { Wm = Wk;  C = 256; }
        else if (m == 1) { Wm = Wv;  C = 256; }
        else if (m == 2) { Wm = Wg;  C = DCTX; }
        else             { Wm = Whb; C = DCTX; }
#pragma unroll 4
        for (int i = 0; i < 16; i++) {
            int d = wid * 64 + i * 4 + g16;
            int oo = d & 255;
            const float* wr = Wm + (size_t)oo * C;
            float p = 0.f;
#pragma unroll
            for (int j = 0; j < 16; j++) p += wr[lane16 + 16 * j] * cs[lane16 + 16 * j];
            if (C == DCTX && lane16 < 3) p += wr[256 + lane16] * cs[256 + lane16];
#pragma unroll
            for (int off = 1; off < 16; off <<= 1) p += __shfl_xor(p, off, 16);
            if (lane16 == 0) {
                if (m == 0)      ks[oo] = p;
                else if (m == 1) vs[oo] = p;
                else if (m == 2) ws[OFF_G + b * DOUT + oo] = 1.f / (1.f + __expf(-(p + bg[oo])));
                else             ws[OFF_HB + b * DOUT + oo] = p;
            }
        }
    }
    __syncthreads();

    const float ko = ks[o];
    const float4* vs4 = (const float4*)vs;
    float pmax = -1e30f;
#pragma unroll 4
    for (int j = q * 16; j < q * 16 + 16; j++) {
        float4 v = vs4[j];
        pmax = fmaxf(pmax, fmaxf(fmaxf(ko * v.x, ko * v.y), fmaxf(ko * v.z, ko * v.w)));
    }
    pm[q * 256 + o] = pmax;
    __syncthreads();
    float m2 = fmaxf(fmaxf(pm[o], pm[256 + o]), fmaxf(pm[512 + o], pm[768 + o]));
    float psum = 0.f;
#pragma unroll 4
    for (int j = q * 16; j < q * 16 + 16; j++) {
        float4 v = vs4[j];
        psum += __expf(ko * v.x - m2) + __expf(ko * v.y - m2)
              + __expf(ko * v.z - m2) + __expf(ko * v.w - m2);
    }
    ps[q * 256 + o] = psum;
    __syncthreads();
    float ri = 1.f / (ps[o] + ps[256 + o] + ps[512 + o] + ps[768 + o]);
    if (q == 0) { rms[o] = m2; ris[o] = ri; }
    __syncthreads();

    const float ve = vs[o];
    float cp = 0.f;
#pragma unroll 4
    for (int o2 = q * 64; o2 < q * 64 + 64; o2++)
        cp += __expf(ks[o2] * ve - rms[o2]) * ris[o2];
    pm[q * 256 + o] = cp;
    __syncthreads();
    float ci = 1.f / (1e-9f + pm[o] + pm[256 + o] + pm[512 + o] + pm[768 + o]);
    unsigned short* Ab = (unsigned short*)(ws + OFF_AB) + (size_t)b * 65536u;
#pragma unroll 4
    for (int o2 = q * 64; o2 < q * 64 + 64; o2++) {
        float a = __expf(ks[o2] * ve - rms[o2]) * ris[o2] * ci;
        Ab[o2 * 256 + o] = f2bf(a);
    }
}

// Fused k4m+k5m: Mt (= Wtc - A-contraction) stays in LDS (XOR-swizzled),
// then WM = Mt @ Wl^T and tb GEMV. grid (2 e-halves, B), 512 threads.
__global__ __launch_bounds__(512) void k45(const float* __restrict__ bl,
                                           const float* __restrict__ btc,
                                           float* __restrict__ ws) {
    const int t = threadIdx.x, wid = t >> 6, l = t & 63;
    const int b = blockIdx.y, et = blockIdx.x;
    const int lrow = l & 15, lk = l >> 4;
    __shared__ unsigned short Mt[128 * 256];   // 64 KB, swizzled: col ^ ((row&7)<<3)
    const unsigned short* Wtcb = (const unsigned short*)(ws + OFF_WTCB);

    // ---- phase A: Mt rows [et*128, et*128+128) ----
    {
        const unsigned short* Ab = (const unsigned short*)(ws + OFF_AB) + (size_t)b * 65536u;
        const int sub = wid >> 2, w2 = wid & 3;
        const int rbase = et * 128 + sub * 64 + (w2 & 1) * 32;
        const int colbase = (w2 >> 1) * 128;
        f32x4 acc[2][8];
#pragma unroll
        for (int i = 0; i < 2; i++)
#pragma unroll
            for (int c = 0; c < 8; c++) acc[i][c] = (f32x4){0.f, 0.f, 0.f, 0.f};
        const unsigned short* ar0 = Wtcb + (rbase + lrow) * 256;
#pragma unroll
        for (int kk = 0; kk < 8; kk++) {
            int ko = kk * 32 + lk * 8;
            bf16x8 a0 = *(const bf16x8*)(ar0 + ko);
            bf16x8 a1 = *(const bf16x8*)(ar0 + 16 * 256 + ko);
            bf16x8 bfr[8];
#pragma unroll
            for (int c = 0; c < 8; c++)
                bfr[c] = *(const bf16x8*)(Ab + (colbase + c * 16 + lrow) * 256 + ko);
#pragma unroll
            for (int c = 0; c < 8; c++) {
                acc[0][c] = __builtin_amdgcn_mfma_f32_16x16x32_bf16(a0, bfr[c], acc[0][c], 0, 0, 0);
                acc[1][c] = __builtin_amdgcn_mfma_f32_16x16x32_bf16(a1, bfr[c], acc[1][c], 0, 0, 0);
            }
        }
#pragma unroll
        for (int t2 = 0; t2 < 2; t2++)
#pragma unroll
            for (int c = 0; c < 8; c++)
#pragma unroll
                for (int r = 0; r < 4; r++) {
                    int grow = rbase + t2 * 16 + lk * 4 + r;
                    int col = colbase + c * 16 + lrow;
                    float idv = bf2f(Wtcb[grow * 256 + col]);
                    int rl = grow - et * 128;
                    Mt[rl * 256 + (col ^ ((rl & 7) << 3))] = f2bf(idv - acc[t2][c][r]);
                }
    }
    __syncthreads();
    // ---- phase B: WM rows = Mt @ Wl^T ----
    {
        const unsigned short* Wltb = (const unsigned short*)(ws + OFF_WLTB);
        const int rl0 = wid * 16;
        f32x4 acc[8];
#pragma unroll
        for (int c = 0; c < 8; c++) acc[c] = (f32x4){0.f, 0.f, 0.f, 0.f};
        const int arow = rl0 + lrow;
        const int asw = (arow & 7) << 3;
#pragma unroll
        for (int kk = 0; kk < 8; kk++) {
            int ko = kk * 32 + lk * 8;
            bf16x8 a0 = *(const bf16x8*)(Mt + arow * 256 + (ko ^ asw));
            bf16x8 bfr[8];
#pragma unroll
            for (int c = 0; c < 8; c++)
                bfr[c] = *(const bf16x8*)(Wltb + (c * 16 + lrow) * 256 + ko);
#pragma unroll
            for (int c = 0; c < 8; c++)
                acc[c] = __builtin_amdgcn_mfma_f32_16x16x32_bf16(a0, bfr[c], acc[c], 0, 0, 0);
        }
        unsigned short* WMBp = (unsigned short*)(ws + OFF_WMB) + (size_t)b * 32768u;
#pragma unroll
        for (int c = 0; c < 8; c++)
#pragma unroll
            for (int r = 0; r < 4; r++) {
                int row = et * 128 + rl0 + lk * 4 + r;
                int col = c * 16 + lrow;
                WMBp[row * 128 + col] = f2bf(acc[c][r]);
            }
    }
    // ---- tb bias GEMV from LDS Mt ----
    if (t < 128) {
        const int rl = t;
        const int sw = (rl & 7) << 3;
        float s = 0.f;
#pragma unroll 4
        for (int j = 0; j < 32; j++) {
            bf16x8 ch = *(const bf16x8*)(Mt + rl * 256 + ((j * 8) ^ sw));
#pragma unroll
            for (int u = 0; u < 8; u++) s += bl[j * 8 + u] * bf2f((unsigned short)ch[u]);
        }
        ws[OFF_TB + b * DOUT + et * 128 + rl] = s + btc[et * 128 + rl];
    }
}

#define LDP 136

// BN-stats GEMM: recompute tt = x @ WM^T + tb (bit-identical to kF's), reduce rows
// to (s1,s2), write atomic-free partials part[b][n]. grid (32 b, 32 nt), 256 thr.
__global__ __launch_bounds__(256) void kS(const float* __restrict__ x,
                                          float* __restrict__ ws) {
    const int t = threadIdx.x;
    const int wid = t >> 6, l = t & 63;
    const int b = blockIdx.x, nt = blockIdx.y;
    const int n0 = nt * 64;
    const int lrow = l & 15, lk = l >> 4;
    __shared__ unsigned short xs[64 * LDP];
    __shared__ float sp1[4][64], sp2[4][64];

    const float4* xg = (const float4*)(x + (size_t)(b * NN + n0) * DIN);
#pragma unroll
    for (int it = 0; it < 8; it++) {
        int idx = it * 256 + t;
        int row = idx >> 5, kq = idx & 31;
        float4 v = xg[idx];
        ushort4 u;
        u.x = f2bf(v.x); u.y = f2bf(v.y); u.z = f2bf(v.z); u.w = f2bf(v.w);
        *(ushort4*)(xs + row * LDP + kq * 4) = u;
    }
    __syncthreads();

    const int colbase = wid * 64;
    f32x4 acc[4][4];
#pragma unroll
    for (int rt = 0; rt < 4; rt++)
#pragma unroll
        for (int ct = 0; ct < 4; ct++) acc[rt][ct] = (f32x4){0.f, 0.f, 0.f, 0.f};
    {
        const unsigned short* wb = (const unsigned short*)(ws + OFF_WMB) + (size_t)b * 32768u;
#pragma unroll
        for (int kk = 0; kk < 4; kk++) {
            int ko = kk * 32 + lk * 8;
            bf16x8 a[4];
#pragma unroll
            for (int rt = 0; rt < 4; rt++)
                a[rt] = *(const bf16x8*)(xs + (rt * 16 + lrow) * LDP + ko);
            bf16x8 bf[4];
#pragma unroll
            for (int ct = 0; ct < 4; ct++)
                bf[ct] = *(const bf16x8*)(wb + (size_t)(colbase + ct * 16 + lrow) * DIN + ko);
#pragma unroll
            for (int rt = 0; rt < 4; rt++)
#pragma unroll
                for (int ct = 0; ct < 4; ct++)
                    acc[rt][ct] = __builtin_amdgcn_mfma_f32_16x16x32_bf16(a[rt], bf[ct], acc[rt][ct], 0, 0, 0);
        }
#pragma unroll
        for (int ct = 0; ct < 4; ct++) {
            float bv = ws[OFF_TB + b * DOUT + colbase + ct * 16 + lrow];
#pragma unroll
            for (int rt = 0; rt < 4; rt++)
#pragma unroll
                for (int r = 0; r < 4; r++) acc[rt][ct][r] += bv;
        }
    }

    float s1[4][4], s2[4][4];
#pragma unroll
    for (int rt = 0; rt < 4; rt++)
#pragma unroll
        for (int r = 0; r < 4; r++) { s1[rt][r] = 0.f; s2[rt][r] = 0.f; }
#pragma unroll
    for (int rt = 0; rt < 4; rt++)
#pragma unroll
        for (int ct = 0; ct < 4; ct++)
#pragma unroll
            for (int r = 0; r < 4; r++) {
                float v = acc[rt][ct][r];
                s1[rt][r] += v; s2[rt][r] += v * v;
            }
#pragma unroll
    for (int off = 1; off < 16; off <<= 1) {
#pragma unroll
        for (int rt = 0; rt < 4; rt++)
#pragma unroll
            for (int r = 0; r < 4; r++) {
                s1[rt][r] += __shfl_xor(s1[rt][r], off, 64);
                s2[rt][r] += __shfl_xor(s2[rt][r], off, 64);
            }
    }
    if (lrow == 0) {
#pragma unroll
        for (int rt = 0; rt < 4; rt++)
#pragma unroll
            for (int r = 0; r < 4; r++) {
                int nidx = rt * 16 + lk * 4 + r;
                sp1[wid][nidx] = s1[rt][r];
                sp2[wid][nidx] = s2[rt][r];
            }
    }
    __syncthreads();
    if (t < 64) {
        float S1 = sp1[0][t] + sp1[1][t] + sp1[2][t] + sp1[3][t];
        float S2 = sp2[0][t] + sp2[1][t] + sp2[2][t] + sp2[3][t];
        ws[OFF_P1 + (size_t)b * NN + n0 + t] = S1;   // coalesced, no atomics
        ws[OFF_P2 + (size_t)b * NN + n0 + t] = S2;
    }
}

// Fused dual-GEMM + BN finalize + epilogue, stream-ordered. tt and x1 in registers;
// per-block BN finalize from L2-hot partials (overlapped with x staging); fused
// k-loop shares a-frags between the two weight sets. grid (32 b, 64 nt).
__global__ __launch_bounds__(256, 4) void kF(const float* __restrict__ x,
                                             const float* __restrict__ bl,
                                             const float* __restrict__ gamma,
                                             const float* __restrict__ beta,
                                             float* __restrict__ out,
                                             float* __restrict__ ws) {
    const int t = threadIdx.x;
    const int wid = t >> 6, l = t & 63;
    const int b = blockIdx.x;
    const int nt = blockIdx.y;
    const int n0 = nt * 32;
    const int lrow = l & 15, lk = l >> 4;
    __shared__ unsigned short xs[32 * LDP];
    __shared__ float scs[32], shs[32];

    // issue x loads first; BN finalize (wave 0) overlaps their latency
    const float4* xg = (const float4*)(x + (size_t)(b * NN + n0) * DIN);
    float4 xv[4];
#pragma unroll
    for (int it = 0; it < 4; it++) xv[it] = xg[it * 256 + t];

    if (t < 32) {
        float S1 = 0.f, S2 = 0.f;
#pragma unroll 8
        for (int b2 = 0; b2 < BB; b2++) {
            S1 += ws[OFF_P1 + (size_t)b2 * NN + n0 + t];
            S2 += ws[OFF_P2 + (size_t)b2 * NN + n0 + t];
        }
        float mean = S1 * (1.f / 8192.f);
        float var  = S2 * (1.f / 8192.f) - mean * mean;
        float sc = gamma[n0 + t] * rsqrtf(fmaxf(var, 0.f) + 1e-5f);
        scs[t] = sc;
        shs[t] = beta[n0 + t] - mean * sc;
    }
#pragma unroll
    for (int it = 0; it < 4; it++) {
        int idx = it * 256 + t;
        int row = idx >> 5, kq = idx & 31;
        ushort4 u;
        u.x = f2bf(xv[it].x); u.y = f2bf(xv[it].y); u.z = f2bf(xv[it].z); u.w = f2bf(xv[it].w);
        *(ushort4*)(xs + row * LDP + kq * 4) = u;
    }
    __syncthreads();

    const int colbase = wid * 64;

    // ---- fused dual GEMM: acc = x@WM^T (tt), acc0 = x@Wl^T (x1) ----
    f32x4 acc[2][4], acc0[2][4];
#pragma unroll
    for (int rt = 0; rt < 2; rt++)
#pragma unroll
        for (int ct = 0; ct < 4; ct++) {
            acc[rt][ct]  = (f32x4){0.f, 0.f, 0.f, 0.f};
            acc0[rt][ct] = (f32x4){0.f, 0.f, 0.f, 0.f};
        }
    {
        const unsigned short* wbM = (const unsigned short*)(ws + OFF_WMB) + (size_t)b * 32768u;
        const unsigned short* wbL = (const unsigned short*)(ws + OFF_WLB);
#pragma unroll
        for (int kk = 0; kk < 4; kk++) {
            int ko = kk * 32 + lk * 8;
            bf16x8 a0 = *(const bf16x8*)(xs + lrow * LDP + ko);
            bf16x8 a1 = *(const bf16x8*)(xs + (16 + lrow) * LDP + ko);
            bf16x8 bf[4];
#pragma unroll
            for (int ct = 0; ct < 4; ct++)
                bf[ct] = *(const bf16x8*)(wbM + (size_t)(colbase + ct * 16 + lrow) * DIN + ko);
#pragma unroll
            for (int ct = 0; ct < 4; ct++) {
                acc[0][ct] = __builtin_amdgcn_mfma_f32_16x16x32_bf16(a0, bf[ct], acc[0][ct], 0, 0, 0);
                acc[1][ct] = __builtin_amdgcn_mfma_f32_16x16x32_bf16(a1, bf[ct], acc[1][ct], 0, 0, 0);
            }
#pragma unroll
            for (int ct = 0; ct < 4; ct++)
                bf[ct] = *(const bf16x8*)(wbL + (size_t)(colbase + ct * 16 + lrow) * DIN + ko);
#pragma unroll
            for (int ct = 0; ct < 4; ct++) {
                acc0[0][ct] = __builtin_amdgcn_mfma_f32_16x16x32_bf16(a0, bf[ct], acc0[0][ct], 0, 0, 0);
                acc0[1][ct] = __builtin_amdgcn_mfma_f32_16x16x32_bf16(a1, bf[ct], acc0[1][ct], 0, 0, 0);
            }
        }
#pragma unroll
        for (int ct = 0; ct < 4; ct++) {
            float bvM = ws[OFF_TB + b * DOUT + colbase + ct * 16 + lrow];
            float bvL = bl[colbase + ct * 16 + lrow];
#pragma unroll
            for (int rt = 0; rt < 2; rt++)
#pragma unroll
                for (int r = 0; r < 4; r++) {
                    acc[rt][ct][r]  += bvM;
                    acc0[rt][ct][r] += bvL;
                }
        }
    }

    // ---- epilogue straight from registers: out = (x1 + relu(bn(tt)))*g + hb ----
    float gv[4], hbv[4];
#pragma unroll
    for (int ct = 0; ct < 4; ct++) {
        int o = colbase + ct * 16 + lrow;
        gv[ct]  = ws[OFF_G  + b * DOUT + o];
        hbv[ct] = ws[OFF_HB + b * DOUT + o];
    }
#pragma unroll
    for (int rt = 0; rt < 2; rt++)
#pragma unroll
        for (int r = 0; r < 4; r++) {
            int nidx = rt * 16 + lk * 4 + r;
            float sc = scs[nidx], sh = shs[nidx];
            int n = n0 + nidx;
#pragma unroll
            for (int ct = 0; ct < 4; ct++) {
                int o = colbase + ct * 16 + lrow;
                float rv = fmaxf(acc[rt][ct][r] * sc + sh, 0.f);
                out[(size_t)((b * NN + n) * DOUT) + o] = (acc0[rt][ct][r] + rv) * gv[ct] + hbv[ct];
            }
        }
}

extern "C" void kernel_launch(void* const* d_in, const int* in_sizes, int n_in,
                              void* d_out, int out_size, void* d_ws, size_t ws_size,
                              hipStream_t stream) {
    const float* ctx   = (const float*)d_in[0];
    const float* x     = (const float*)d_in[1];
    const float* Wl    = (const float*)d_in[2];
    const float* bl    = (const float*)d_in[3];
    const float* Whb   = (const float*)d_in[4];
    const float* Wg    = (const float*)d_in[5];
    const float* bg    = (const float*)d_in[6];
    const float* Wk    = (const float*)d_in[7];
    const float* Wv    = (const float*)d_in[8];
    const float* Wtc   = (const float*)d_in[9];
    const float* btc   = (const float*)d_in[10];
    const float* gamma = (const float*)d_in[11];
    const float* beta  = (const float*)d_in[12];
    float* out = (float*)d_out;
    float* ws  = (float*)d_ws;

    kPW <<<34, 1024, 0, stream>>>(ctx, bg, Wl, Wtc, Wk, Wv, Wg, Whb, ws);
    k45 <<<dim3(2, BB), 512, 0, stream>>>(bl, btc, ws);
    kS  <<<dim3(BB, 32), 256, 0, stream>>>(x, ws);
    kF  <<<dim3(BB, 64), 256, 0, stream>>>(x, bl, gamma, beta, out, ws);
}

// Round 5
// 239.749 us; speedup vs baseline: 1.1331x; 1.1331x over previous
//
#include <hip/hip_runtime.h>
#include <hip/hip_bf16.h>

#define BB   32
#define NN   2048
#define DIN  128
#define DOUT 256
#define DCTX 259

// ---- workspace layout (float-slot offsets) ----
#define OFF_AB   0u          // A  bf16 [B][256][256] (dead before kF)
#define OFF_WMB  16777216u   // WM bf16 [B][256 e][128 i] = 524288
#define OFF_WLB  17301504u   // W_layer bf16 [256 o][128 i] = 16384
#define OFF_WLTB 17317888u   // W_layer^T bf16 [128 i][256 o] = 16384
#define OFF_WTCB 17334272u   // W_tc bf16 [256 e][256 o] = 32768
#define OFF_G    17367040u
#define OFF_HB   17375232u
#define OFF_TB   17383424u
#define OFF_WKT  17391616u   // [256 c][256 o] fp32
#define OFF_WVT  17457152u
#define OFF_WGT  17522688u   // [259 c][256 o]
#define OFF_WHT  17588992u
#define OFF_P1   17655296u   // BN partial s1 [32 b][2048 n] fp32
#define OFF_P2   17720832u   // BN partial s2 [32 b][2048 n] fp32
// end 17786368 slots ≈ 71.1 MB

typedef short bf16x8 __attribute__((ext_vector_type(8)));
typedef float f32x4  __attribute__((ext_vector_type(4)));

static __device__ inline unsigned short f2bf(float f) {
    __hip_bfloat16 h = __float2bfloat16(f);
    return *(unsigned short*)&h;
}
static __device__ inline float bf2f(unsigned short u) {
    unsigned v = ((unsigned)u) << 16;
    float f;
    __builtin_memcpy(&f, &v, 4);
    return f;
}

// weight packing. grid 44. (reverted to R3 proven version)
__global__ void kXW(const float* __restrict__ Wl, const float* __restrict__ Wtc,
                    const float* __restrict__ Wk, const float* __restrict__ Wv,
                    const float* __restrict__ Wg, const float* __restrict__ Whb,
                    float* __restrict__ ws) {
    unsigned bb = blockIdx.x, t = threadIdx.x;
    if (bb < 8u) {
        unsigned base = bb * 8192u;
        unsigned short* dst = (unsigned short*)(ws + OFF_WTCB);
#pragma unroll
        for (int j = 0; j < 32; j++) {
            unsigned i = base + (unsigned)j * 256u + t;
            dst[i] = f2bf(Wtc[i]);
        }
    } else if (bb == 8u) {
        unsigned short* dst = (unsigned short*)(ws + OFF_WLTB);   // [i][o]
        for (unsigned idx = t; idx < 32768u; idx += 256u) {
            unsigned i = idx >> 8, o = idx & 255u;
            dst[idx] = f2bf(Wl[o * 128u + i]);
        }
    } else if (bb == 9u) {
        unsigned short* dst = (unsigned short*)(ws + OFF_WLB);    // [o][i]
        for (unsigned idx = t; idx < 32768u; idx += 256u) dst[idx] = f2bf(Wl[idx]);
    } else {
        unsigned j = bb - 10u;
        const float* src; float* dst; unsigned C, c0;
        if (j < 8u)       { src = Wk;  dst = ws + OFF_WKT; C = 256; c0 = j * 32u; }
        else if (j < 16u) { src = Wv;  dst = ws + OFF_WVT; C = 256; c0 = (j - 8u) * 32u; }
        else if (j < 25u) { src = Wg;  dst = ws + OFF_WGT; C = 259; c0 = (j - 16u) * 32u; }
        else              { src = Whb; dst = ws + OFF_WHT; C = 259; c0 = (j - 25u) * 32u; }
        for (unsigned cc = c0; cc < c0 + 32u && cc < C; cc++)
            dst[cc * 256u + t] = src[t * C + cc];
    }
}

// Fused prep, 1024 threads: coalesced GEMVs + split softmax stats + A bf16. grid B.
// (reverted to R3 proven version)
__global__ __launch_bounds__(1024) void kP(const float* __restrict__ ctx,
                                           const float* __restrict__ bg,
                                           float* __restrict__ ws) {
    const int b = blockIdx.x, t = threadIdx.x;
    const int o = t & 255, q = t >> 8;
    __shared__ __align__(16) float cs[260];
    __shared__ __align__(16) float ks[256], vs[256], rms[256], ris[256];
    __shared__ float pm[1024], ps[1024];
    for (int i = t; i < DCTX; i += 1024) cs[i] = ctx[b * DCTX + i];
    __syncthreads();

    {
        const float* WT; int C;
        if (q == 0)      { WT = ws + OFF_WKT; C = 256; }
        else if (q == 1) { WT = ws + OFF_WVT; C = 256; }
        else if (q == 2) { WT = ws + OFF_WGT; C = DCTX; }
        else             { WT = ws + OFF_WHT; C = DCTX; }
        float s = 0.f;
#pragma unroll 8
        for (int c = 0; c < C; c++) s += WT[c * 256 + o] * cs[c];
        if (q == 0)      ks[o] = s;
        else if (q == 1) vs[o] = s;
        else if (q == 2) ws[OFF_G + b * DOUT + o] = 1.f / (1.f + __expf(-(s + bg[o])));
        else             ws[OFF_HB + b * DOUT + o] = s;
    }
    __syncthreads();

    const float ko = ks[o];
    const float4* vs4 = (const float4*)vs;
    float pmax = -1e30f;
#pragma unroll 4
    for (int j = q * 16; j < q * 16 + 16; j++) {
        float4 v = vs4[j];
        pmax = fmaxf(pmax, fmaxf(fmaxf(ko * v.x, ko * v.y), fmaxf(ko * v.z, ko * v.w)));
    }
    pm[q * 256 + o] = pmax;
    __syncthreads();
    float m = fmaxf(fmaxf(pm[o], pm[256 + o]), fmaxf(pm[512 + o], pm[768 + o]));
    float psum = 0.f;
#pragma unroll 4
    for (int j = q * 16; j < q * 16 + 16; j++) {
        float4 v = vs4[j];
        psum += __expf(ko * v.x - m) + __expf(ko * v.y - m)
              + __expf(ko * v.z - m) + __expf(ko * v.w - m);
    }
    ps[q * 256 + o] = psum;
    __syncthreads();
    float ri = 1.f / (ps[o] + ps[256 + o] + ps[512 + o] + ps[768 + o]);
    if (q == 0) { rms[o] = m; ris[o] = ri; }
    __syncthreads();

    const float ve = vs[o];
    float cp = 0.f;
#pragma unroll 4
    for (int o2 = q * 64; o2 < q * 64 + 64; o2++)
        cp += __expf(ks[o2] * ve - rms[o2]) * ris[o2];
    pm[q * 256 + o] = cp;
    __syncthreads();
    float ci = 1.f / (1e-9f + pm[o] + pm[256 + o] + pm[512 + o] + pm[768 + o]);
    unsigned short* Ab = (unsigned short*)(ws + OFF_AB) + (size_t)b * 65536u;
#pragma unroll 4
    for (int o2 = q * 64; o2 < q * 64 + 64; o2++) {
        float a = __expf(ks[o2] * ve - rms[o2]) * ris[o2] * ci;
        Ab[o2 * 256 + o] = f2bf(a);
    }
}

// Fused k4m+k5m: Mt (= Wtc - A-contraction) stays in LDS (XOR-swizzled),
// then WM = Mt @ Wl^T and tb GEMV. grid (2 e-halves, B), 512 threads.
__global__ __launch_bounds__(512) void k45(const float* __restrict__ bl,
                                           const float* __restrict__ btc,
                                           float* __restrict__ ws) {
    const int t = threadIdx.x, wid = t >> 6, l = t & 63;
    const int b = blockIdx.y, et = blockIdx.x;
    const int lrow = l & 15, lk = l >> 4;
    __shared__ unsigned short Mt[128 * 256];   // 64 KB, swizzled: col ^ ((row&7)<<3)
    const unsigned short* Wtcb = (const unsigned short*)(ws + OFF_WTCB);

    // ---- phase A: Mt rows [et*128, et*128+128) ----
    {
        const unsigned short* Ab = (const unsigned short*)(ws + OFF_AB) + (size_t)b * 65536u;
        const int sub = wid >> 2, w2 = wid & 3;
        const int rbase = et * 128 + sub * 64 + (w2 & 1) * 32;
        const int colbase = (w2 >> 1) * 128;
        f32x4 acc[2][8];
#pragma unroll
        for (int i = 0; i < 2; i++)
#pragma unroll
            for (int c = 0; c < 8; c++) acc[i][c] = (f32x4){0.f, 0.f, 0.f, 0.f};
        const unsigned short* ar0 = Wtcb + (rbase + lrow) * 256;
#pragma unroll
        for (int kk = 0; kk < 8; kk++) {
            int ko = kk * 32 + lk * 8;
            bf16x8 a0 = *(const bf16x8*)(ar0 + ko);
            bf16x8 a1 = *(const bf16x8*)(ar0 + 16 * 256 + ko);
            bf16x8 bfr[8];
#pragma unroll
            for (int c = 0; c < 8; c++)
                bfr[c] = *(const bf16x8*)(Ab + (colbase + c * 16 + lrow) * 256 + ko);
#pragma unroll
            for (int c = 0; c < 8; c++) {
                acc[0][c] = __builtin_amdgcn_mfma_f32_16x16x32_bf16(a0, bfr[c], acc[0][c], 0, 0, 0);
                acc[1][c] = __builtin_amdgcn_mfma_f32_16x16x32_bf16(a1, bfr[c], acc[1][c], 0, 0, 0);
            }
        }
#pragma unroll
        for (int t2 = 0; t2 < 2; t2++)
#pragma unroll
            for (int c = 0; c < 8; c++)
#pragma unroll
                for (int r = 0; r < 4; r++) {
                    int grow = rbase + t2 * 16 + lk * 4 + r;
                    int col = colbase + c * 16 + lrow;
                    float idv = bf2f(Wtcb[grow * 256 + col]);
                    int rl = grow - et * 128;
                    Mt[rl * 256 + (col ^ ((rl & 7) << 3))] = f2bf(idv - acc[t2][c][r]);
                }
    }
    __syncthreads();
    // ---- phase B: WM rows = Mt @ Wl^T ----
    {
        const unsigned short* Wltb = (const unsigned short*)(ws + OFF_WLTB);
        const int rl0 = wid * 16;
        f32x4 acc[8];
#pragma unroll
        for (int c = 0; c < 8; c++) acc[c] = (f32x4){0.f, 0.f, 0.f, 0.f};
        const int arow = rl0 + lrow;
        const int asw = (arow & 7) << 3;
#pragma unroll
        for (int kk = 0; kk < 8; kk++) {
            int ko = kk * 32 + lk * 8;
            bf16x8 a0 = *(const bf16x8*)(Mt + arow * 256 + (ko ^ asw));
            bf16x8 bfr[8];
#pragma unroll
            for (int c = 0; c < 8; c++)
                bfr[c] = *(const bf16x8*)(Wltb + (c * 16 + lrow) * 256 + ko);
#pragma unroll
            for (int c = 0; c < 8; c++)
                acc[c] = __builtin_amdgcn_mfma_f32_16x16x32_bf16(a0, bfr[c], acc[c], 0, 0, 0);
        }
        unsigned short* WMBp = (unsigned short*)(ws + OFF_WMB) + (size_t)b * 32768u;
#pragma unroll
        for (int c = 0; c < 8; c++)
#pragma unroll
            for (int r = 0; r < 4; r++) {
                int row = et * 128 + rl0 + lk * 4 + r;
                int col = c * 16 + lrow;
                WMBp[row * 128 + col] = f2bf(acc[c][r]);
            }
    }
    // ---- tb bias GEMV from LDS Mt ----
    if (t < 128) {
        const int rl = t;
        const int sw = (rl & 7) << 3;
        float s = 0.f;
#pragma unroll 4
        for (int j = 0; j < 32; j++) {
            bf16x8 ch = *(const bf16x8*)(Mt + rl * 256 + ((j * 8) ^ sw));
#pragma unroll
            for (int u = 0; u < 8; u++) s += bl[j * 8 + u] * bf2f((unsigned short)ch[u]);
        }
        ws[OFF_TB + b * DOUT + et * 128 + rl] = s + btc[et * 128 + rl];
    }
}

#define LDP 136

// BN-stats GEMM: recompute tt = x @ WM^T + tb, reduce rows to (s1,s2), write
// atomic-free partials part[b][n]. grid (32 b, 32 nt), 256 thr.
__global__ __launch_bounds__(256) void kS(const float* __restrict__ x,
                                          float* __restrict__ ws) {
    const int t = threadIdx.x;
    const int wid = t >> 6, l = t & 63;
    const int b = blockIdx.x, nt = blockIdx.y;
    const int n0 = nt * 64;
    const int lrow = l & 15, lk = l >> 4;
    __shared__ unsigned short xs[64 * LDP];
    __shared__ float sp1[4][64], sp2[4][64];

    const float4* xg = (const float4*)(x + (size_t)(b * NN + n0) * DIN);
#pragma unroll
    for (int it = 0; it < 8; it++) {
        int idx = it * 256 + t;
        int row = idx >> 5, kq = idx & 31;
        float4 v = xg[idx];
        ushort4 u;
        u.x = f2bf(v.x); u.y = f2bf(v.y); u.z = f2bf(v.z); u.w = f2bf(v.w);
        *(ushort4*)(xs + row * LDP + kq * 4) = u;
    }
    __syncthreads();

    const int colbase = wid * 64;
    f32x4 acc[4][4];
#pragma unroll
    for (int rt = 0; rt < 4; rt++)
#pragma unroll
        for (int ct = 0; ct < 4; ct++) acc[rt][ct] = (f32x4){0.f, 0.f, 0.f, 0.f};
    {
        const unsigned short* wb = (const unsigned short*)(ws + OFF_WMB) + (size_t)b * 32768u;
#pragma unroll
        for (int kk = 0; kk < 4; kk++) {
            int ko = kk * 32 + lk * 8;
            bf16x8 a[4];
#pragma unroll
            for (int rt = 0; rt < 4; rt++)
                a[rt] = *(const bf16x8*)(xs + (rt * 16 + lrow) * LDP + ko);
            bf16x8 bf[4];
#pragma unroll
            for (int ct = 0; ct < 4; ct++)
                bf[ct] = *(const bf16x8*)(wb + (size_t)(colbase + ct * 16 + lrow) * DIN + ko);
#pragma unroll
            for (int rt = 0; rt < 4; rt++)
#pragma unroll
                for (int ct = 0; ct < 4; ct++)
                    acc[rt][ct] = __builtin_amdgcn_mfma_f32_16x16x32_bf16(a[rt], bf[ct], acc[rt][ct], 0, 0, 0);
        }
#pragma unroll
        for (int ct = 0; ct < 4; ct++) {
            float bv = ws[OFF_TB + b * DOUT + colbase + ct * 16 + lrow];
#pragma unroll
            for (int rt = 0; rt < 4; rt++)
#pragma unroll
                for (int r = 0; r < 4; r++) acc[rt][ct][r] += bv;
        }
    }

    float s1[4][4], s2[4][4];
#pragma unroll
    for (int rt = 0; rt < 4; rt++)
#pragma unroll
        for (int r = 0; r < 4; r++) { s1[rt][r] = 0.f; s2[rt][r] = 0.f; }
#pragma unroll
    for (int rt = 0; rt < 4; rt++)
#pragma unroll
        for (int ct = 0; ct < 4; ct++)
#pragma unroll
            for (int r = 0; r < 4; r++) {
                float v = acc[rt][ct][r];
                s1[rt][r] += v; s2[rt][r] += v * v;
            }
#pragma unroll
    for (int off = 1; off < 16; off <<= 1) {
#pragma unroll
        for (int rt = 0; rt < 4; rt++)
#pragma unroll
            for (int r = 0; r < 4; r++) {
                s1[rt][r] += __shfl_xor(s1[rt][r], off, 64);
                s2[rt][r] += __shfl_xor(s2[rt][r], off, 64);
            }
    }
    if (lrow == 0) {
#pragma unroll
        for (int rt = 0; rt < 4; rt++)
#pragma unroll
            for (int r = 0; r < 4; r++) {
                int nidx = rt * 16 + lk * 4 + r;
                sp1[wid][nidx] = s1[rt][r];
                sp2[wid][nidx] = s2[rt][r];
            }
    }
    __syncthreads();
    if (t < 64) {
        float S1 = sp1[0][t] + sp1[1][t] + sp1[2][t] + sp1[3][t];
        float S2 = sp2[0][t] + sp2[1][t] + sp2[2][t] + sp2[3][t];
        ws[OFF_P1 + (size_t)b * NN + n0 + t] = S1;
        ws[OFF_P2 + (size_t)b * NN + n0 + t] = S2;
    }
}

// Fused dual-GEMM + BN finalize + epilogue, 64-row tiles. tt and x1 in registers;
// BN finalize from L2-hot partials overlapped with x staging; shared a-frags feed
// both weight sets (128 MFMA/wave back-to-back). grid (32 b, 32 nt), 2 blocks/CU.
__global__ __launch_bounds__(256, 2) void kF(const float* __restrict__ x,
                                             const float* __restrict__ bl,
                                             const float* __restrict__ gamma,
                                             const float* __restrict__ beta,
                                             float* __restrict__ out,
                                             float* __restrict__ ws) {
    const int t = threadIdx.x;
    const int wid = t >> 6, l = t & 63;
    const int b = blockIdx.x;
    const int nt = blockIdx.y;
    const int n0 = nt * 64;
    const int lrow = l & 15, lk = l >> 4;
    __shared__ unsigned short xs[64 * LDP];
    __shared__ float scs[64], shs[64];

    // issue x loads first; BN finalize overlaps their latency
    const float4* xg = (const float4*)(x + (size_t)(b * NN + n0) * DIN);
    float4 xv[8];
#pragma unroll
    for (int it = 0; it < 8; it++) xv[it] = xg[it * 256 + t];

    if (t < 64) {
        float S1 = 0.f, S2 = 0.f;
#pragma unroll 8
        for (int b2 = 0; b2 < BB; b2++) {
            S1 += ws[OFF_P1 + (size_t)b2 * NN + n0 + t];
            S2 += ws[OFF_P2 + (size_t)b2 * NN + n0 + t];
        }
        float mean = S1 * (1.f / 8192.f);
        float var  = S2 * (1.f / 8192.f) - mean * mean;
        float sc = gamma[n0 + t] * rsqrtf(fmaxf(var, 0.f) + 1e-5f);
        scs[t] = sc;
        shs[t] = beta[n0 + t] - mean * sc;
    }
#pragma unroll
    for (int it = 0; it < 8; it++) {
        int idx = it * 256 + t;
        int row = idx >> 5, kq = idx & 31;
        ushort4 u;
        u.x = f2bf(xv[it].x); u.y = f2bf(xv[it].y); u.z = f2bf(xv[it].z); u.w = f2bf(xv[it].w);
        *(ushort4*)(xs + row * LDP + kq * 4) = u;
    }
    __syncthreads();

    const int colbase = wid * 64;

    // ---- fused dual GEMM over 64 rows: acc = x@WM^T (tt), acc0 = x@Wl^T (x1) ----
    f32x4 acc[4][4], acc0[4][4];
#pragma unroll
    for (int rt = 0; rt < 4; rt++)
#pragma unroll
        for (int ct = 0; ct < 4; ct++) {
            acc[rt][ct]  = (f32x4){0.f, 0.f, 0.f, 0.f};
            acc0[rt][ct] = (f32x4){0.f, 0.f, 0.f, 0.f};
        }
    {
        const unsigned short* wbM = (const unsigned short*)(ws + OFF_WMB) + (size_t)b * 32768u;
        const unsigned short* wbL = (const unsigned short*)(ws + OFF_WLB);
#pragma unroll
        for (int kk = 0; kk < 4; kk++) {
            int ko = kk * 32 + lk * 8;
            bf16x8 a[4];
#pragma unroll
            for (int rt = 0; rt < 4; rt++)
                a[rt] = *(const bf16x8*)(xs + (rt * 16 + lrow) * LDP + ko);
            bf16x8 bf[4];
#pragma unroll
            for (int ct = 0; ct < 4; ct++)
                bf[ct] = *(const bf16x8*)(wbM + (size_t)(colbase + ct * 16 + lrow) * DIN + ko);
#pragma unroll
            for (int rt = 0; rt < 4; rt++)
#pragma unroll
                for (int ct = 0; ct < 4; ct++)
                    acc[rt][ct] = __builtin_amdgcn_mfma_f32_16x16x32_bf16(a[rt], bf[ct], acc[rt][ct], 0, 0, 0);
#pragma unroll
            for (int ct = 0; ct < 4; ct++)
                bf[ct] = *(const bf16x8*)(wbL + (size_t)(colbase + ct * 16 + lrow) * DIN + ko);
#pragma unroll
            for (int rt = 0; rt < 4; rt++)
#pragma unroll
                for (int ct = 0; ct < 4; ct++)
                    acc0[rt][ct] = __builtin_amdgcn_mfma_f32_16x16x32_bf16(a[rt], bf[ct], acc0[rt][ct], 0, 0, 0);
        }
#pragma unroll
        for (int ct = 0; ct < 4; ct++) {
            float bvM = ws[OFF_TB + b * DOUT + colbase + ct * 16 + lrow];
            float bvL = bl[colbase + ct * 16 + lrow];
#pragma unroll
            for (int rt = 0; rt < 4; rt++)
#pragma unroll
                for (int r = 0; r < 4; r++) {
                    acc[rt][ct][r]  += bvM;
                    acc0[rt][ct][r] += bvL;
                }
        }
    }

    // ---- epilogue straight from registers: out = (x1 + relu(bn(tt)))*g + hb ----
    float gv[4], hbv[4];
#pragma unroll
    for (int ct = 0; ct < 4; ct++) {
        int o = colbase + ct * 16 + lrow;
        gv[ct]  = ws[OFF_G  + b * DOUT + o];
        hbv[ct] = ws[OFF_HB + b * DOUT + o];
    }
#pragma unroll
    for (int rt = 0; rt < 4; rt++)
#pragma unroll
        for (int r = 0; r < 4; r++) {
            int nidx = rt * 16 + lk * 4 + r;
            float sc = scs[nidx], sh = shs[nidx];
            int n = n0 + nidx;
#pragma unroll
            for (int ct = 0; ct < 4; ct++) {
                int o = colbase + ct * 16 + lrow;
                float rv = fmaxf(acc[rt][ct][r] * sc + sh, 0.f);
                out[(size_t)((b * NN + n) * DOUT) + o] = (acc0[rt][ct][r] + rv) * gv[ct] + hbv[ct];
            }
        }
}

extern "C" void kernel_launch(void* const* d_in, const int* in_sizes, int n_in,
                              void* d_out, int out_size, void* d_ws, size_t ws_size,
                              hipStream_t stream) {
    const float* ctx   = (const float*)d_in[0];
    const float* x     = (const float*)d_in[1];
    const float* Wl    = (const float*)d_in[2];
    const float* bl    = (const float*)d_in[3];
    const float* Whb   = (const float*)d_in[4];
    const float* Wg    = (const float*)d_in[5];
    const float* bg    = (const float*)d_in[6];
    const float* Wk    = (const float*)d_in[7];
    const float* Wv    = (const float*)d_in[8];
    const float* Wtc   = (const float*)d_in[9];
    const float* btc   = (const float*)d_in[10];
    const float* gamma = (const float*)d_in[11];
    const float* beta  = (const float*)d_in[12];
    float* out = (float*)d_out;
    float* ws  = (float*)d_ws;

    kXW <<<44, 256, 0, stream>>>(Wl, Wtc, Wk, Wv, Wg, Whb, ws);
    kP  <<<BB, 1024, 0, stream>>>(ctx, bg, ws);
    k45 <<<dim3(2, BB), 512, 0, stream>>>(bl, btc, ws);
    kS  <<<dim3(BB, 32), 256, 0, stream>>>(x, ws);
    kF  <<<dim3(BB, 32), 256, 0, stream>>>(x, bl, gamma, beta, out, ws);
}

// Round 6
// 237.162 us; speedup vs baseline: 1.1454x; 1.0109x over previous
//
#include <hip/hip_runtime.h>
#include <hip/hip_bf16.h>

#define BB   32
#define NN   2048
#define DIN  128
#define DOUT 256
#define DCTX 259

// ---- workspace layout (float-slot offsets) ----
#define OFF_AB   0u          // A  bf16 [B][256][256] (dead before kF)
#define OFF_WMB  16777216u   // WM bf16 [B][256 e][128 i] = 524288
#define OFF_WLB  17301504u   // W_layer bf16 [256 o][128 i] = 16384
#define OFF_WLTB 17317888u   // W_layer^T bf16 [128 i][256 o] = 16384
#define OFF_WTCB 17334272u   // W_tc bf16 [256 e][256 o] = 32768
#define OFF_G    17367040u
#define OFF_HB   17375232u
#define OFF_TB   17383424u
#define OFF_P1   17655296u   // BN partial s1 [32 b][2048 n] fp32
#define OFF_P2   17720832u   // BN partial s2 [32 b][2048 n] fp32
// end 17786368 slots ≈ 71.1 MB

typedef short bf16x8 __attribute__((ext_vector_type(8)));
typedef float f32x4  __attribute__((ext_vector_type(4)));

static __device__ inline unsigned short f2bf(float f) {
    __hip_bfloat16 h = __float2bfloat16(f);
    return *(unsigned short*)&h;
}
static __device__ inline float bf2f(unsigned short u) {
    unsigned v = ((unsigned)u) << 16;
    float f;
    __builtin_memcpy(&f, &v, 4);
    return f;
}

// weight packing (bf16 only; fp32 transposes eliminated). grid 10.
__global__ void kXW(const float* __restrict__ Wl, const float* __restrict__ Wtc,
                    float* __restrict__ ws) {
    unsigned bb = blockIdx.x, t = threadIdx.x;
    if (bb < 8u) {
        unsigned base = bb * 8192u;
        unsigned short* dst = (unsigned short*)(ws + OFF_WTCB);
#pragma unroll
        for (int j = 0; j < 32; j++) {
            unsigned i = base + (unsigned)j * 256u + t;
            dst[i] = f2bf(Wtc[i]);
        }
    } else if (bb == 8u) {
        unsigned short* dst = (unsigned short*)(ws + OFF_WLTB);   // [i][o]
        for (unsigned idx = t; idx < 32768u; idx += 256u) {
            unsigned i = idx >> 8, o = idx & 255u;
            dst[idx] = f2bf(Wl[o * 128u + i]);
        }
    } else {
        unsigned short* dst = (unsigned short*)(ws + OFF_WLB);    // [o][i]
        for (unsigned idx = t; idx < 32768u; idx += 256u) dst[idx] = f2bf(Wl[idx]);
    }
}

// Fused prep, 1024 threads: direct row-major GEMVs (thread-per-o, per-lane row
// stream, L2-shared across blocks) + split softmax stats + A bf16. grid B.
__global__ __launch_bounds__(1024) void kP(const float* __restrict__ ctx,
                                           const float* __restrict__ bg,
                                           const float* __restrict__ Wk,
                                           const float* __restrict__ Wv,
                                           const float* __restrict__ Wg,
                                           const float* __restrict__ Whb,
                                           float* __restrict__ ws) {
    const int b = blockIdx.x, t = threadIdx.x;
    const int o = t & 255, q = t >> 8;
    __shared__ __align__(16) float cs[260];
    __shared__ __align__(16) float ks[256], vs[256], rms[256], ris[256];
    __shared__ float pm[1024], ps[1024];
    for (int i = t; i < DCTX; i += 1024) cs[i] = ctx[b * DCTX + i];
    __syncthreads();

    {
        const float* Wm; int C;
        if (q == 0)      { Wm = Wk;  C = 256; }
        else if (q == 1) { Wm = Wv;  C = 256; }
        else if (q == 2) { Wm = Wg;  C = DCTX; }
        else             { Wm = Whb; C = DCTX; }
        const float* wr = Wm + (size_t)o * C;
        float s = 0.f;
#pragma unroll 16
        for (int c = 0; c < 256; c++) s += wr[c] * cs[c];
        if (C == DCTX) s += wr[256] * cs[256] + wr[257] * cs[257] + wr[258] * cs[258];
        if (q == 0)      ks[o] = s;
        else if (q == 1) vs[o] = s;
        else if (q == 2) ws[OFF_G + b * DOUT + o] = 1.f / (1.f + __expf(-(s + bg[o])));
        else             ws[OFF_HB + b * DOUT + o] = s;
    }
    __syncthreads();

    const float ko = ks[o];
    const float4* vs4 = (const float4*)vs;
    float pmax = -1e30f;
#pragma unroll 4
    for (int j = q * 16; j < q * 16 + 16; j++) {
        float4 v = vs4[j];
        pmax = fmaxf(pmax, fmaxf(fmaxf(ko * v.x, ko * v.y), fmaxf(ko * v.z, ko * v.w)));
    }
    pm[q * 256 + o] = pmax;
    __syncthreads();
    float m = fmaxf(fmaxf(pm[o], pm[256 + o]), fmaxf(pm[512 + o], pm[768 + o]));
    float psum = 0.f;
#pragma unroll 4
    for (int j = q * 16; j < q * 16 + 16; j++) {
        float4 v = vs4[j];
        psum += __expf(ko * v.x - m) + __expf(ko * v.y - m)
              + __expf(ko * v.z - m) + __expf(ko * v.w - m);
    }
    ps[q * 256 + o] = psum;
    __syncthreads();
    float ri = 1.f / (ps[o] + ps[256 + o] + ps[512 + o] + ps[768 + o]);
    if (q == 0) { rms[o] = m; ris[o] = ri; }
    __syncthreads();

    const float ve = vs[o];
    float cp = 0.f;
#pragma unroll 4
    for (int o2 = q * 64; o2 < q * 64 + 64; o2++)
        cp += __expf(ks[o2] * ve - rms[o2]) * ris[o2];
    pm[q * 256 + o] = cp;
    __syncthreads();
    float ci = 1.f / (1e-9f + pm[o] + pm[256 + o] + pm[512 + o] + pm[768 + o]);
    unsigned short* Ab = (unsigned short*)(ws + OFF_AB) + (size_t)b * 65536u;
#pragma unroll 4
    for (int o2 = q * 64; o2 < q * 64 + 64; o2++) {
        float a = __expf(ks[o2] * ve - rms[o2]) * ris[o2] * ci;
        Ab[o2 * 256 + o] = f2bf(a);
    }
}

// Fused k4m+k5m, 64-row et-quarters for 2x parallelism. Mt in LDS (XOR-swizzled),
// then WM = Mt @ Wl^T and tb GEMV. grid (4 e-quarters, B), 512 threads.
__global__ __launch_bounds__(512) void k45(const float* __restrict__ bl,
                                           const float* __restrict__ btc,
                                           float* __restrict__ ws) {
    const int t = threadIdx.x, wid = t >> 6, l = t & 63;
    const int b = blockIdx.y, et = blockIdx.x;
    const int lrow = l & 15, lk = l >> 4;
    __shared__ unsigned short Mt[64 * 256];   // 32 KB, swizzled: col ^ ((row&7)<<3)
    const unsigned short* Wtcb = (const unsigned short*)(ws + OFF_WTCB);

    // ---- phase A: Mt rows [et*64, et*64+64), waves 2 rows x 4 cols ----
    {
        const unsigned short* Ab = (const unsigned short*)(ws + OFF_AB) + (size_t)b * 65536u;
        const int w_r = wid >> 2, w_c = wid & 3;
        const int rbase = et * 64 + w_r * 32;
        const int colbase = w_c * 64;
        f32x4 acc[2][4];
#pragma unroll
        for (int i = 0; i < 2; i++)
#pragma unroll
            for (int c = 0; c < 4; c++) acc[i][c] = (f32x4){0.f, 0.f, 0.f, 0.f};
        const unsigned short* ar0 = Wtcb + (rbase + lrow) * 256;
#pragma unroll
        for (int kk = 0; kk < 8; kk++) {
            int ko = kk * 32 + lk * 8;
            bf16x8 a0 = *(const bf16x8*)(ar0 + ko);
            bf16x8 a1 = *(const bf16x8*)(ar0 + 16 * 256 + ko);
            bf16x8 bfr[4];
#pragma unroll
            for (int c = 0; c < 4; c++)
                bfr[c] = *(const bf16x8*)(Ab + (colbase + c * 16 + lrow) * 256 + ko);
#pragma unroll
            for (int c = 0; c < 4; c++) {
                acc[0][c] = __builtin_amdgcn_mfma_f32_16x16x32_bf16(a0, bfr[c], acc[0][c], 0, 0, 0);
                acc[1][c] = __builtin_amdgcn_mfma_f32_16x16x32_bf16(a1, bfr[c], acc[1][c], 0, 0, 0);
            }
        }
#pragma unroll
        for (int t2 = 0; t2 < 2; t2++)
#pragma unroll
            for (int c = 0; c < 4; c++)
#pragma unroll
                for (int r = 0; r < 4; r++) {
                    int grow = rbase + t2 * 16 + lk * 4 + r;
                    int col = colbase + c * 16 + lrow;
                    float idv = bf2f(Wtcb[grow * 256 + col]);
                    int rl = grow - et * 64;
                    Mt[rl * 256 + (col ^ ((rl & 7) << 3))] = f2bf(idv - acc[t2][c][r]);
                }
    }
    __syncthreads();
    // ---- phase B: WM rows [et*64..+64) = Mt @ Wl^T, waves 2 rows x 4 cols(32) ----
    {
        const unsigned short* Wltb = (const unsigned short*)(ws + OFF_WLTB);
        const int w_r = wid >> 2, w_c = wid & 3;
        const int rl0 = w_r * 32;
        const int colb = w_c * 32;
        f32x4 acc[2][2];
#pragma unroll
        for (int i = 0; i < 2; i++)
#pragma unroll
            for (int c = 0; c < 2; c++) acc[i][c] = (f32x4){0.f, 0.f, 0.f, 0.f};
        const int arow0 = rl0 + lrow, arow1 = rl0 + 16 + lrow;
        const int asw0 = (arow0 & 7) << 3, asw1 = (arow1 & 7) << 3;
#pragma unroll
        for (int kk = 0; kk < 8; kk++) {
            int ko = kk * 32 + lk * 8;
            bf16x8 a0 = *(const bf16x8*)(Mt + arow0 * 256 + (ko ^ asw0));
            bf16x8 a1 = *(const bf16x8*)(Mt + arow1 * 256 + (ko ^ asw1));
            bf16x8 bfr[2];
#pragma unroll
            for (int c = 0; c < 2; c++)
                bfr[c] = *(const bf16x8*)(Wltb + (colb + c * 16 + lrow) * 256 + ko);
#pragma unroll
            for (int c = 0; c < 2; c++) {
                acc[0][c] = __builtin_amdgcn_mfma_f32_16x16x32_bf16(a0, bfr[c], acc[0][c], 0, 0, 0);
                acc[1][c] = __builtin_amdgcn_mfma_f32_16x16x32_bf16(a1, bfr[c], acc[1][c], 0, 0, 0);
            }
        }
        unsigned short* WMBp = (unsigned short*)(ws + OFF_WMB) + (size_t)b * 32768u;
#pragma unroll
        for (int t2 = 0; t2 < 2; t2++)
#pragma unroll
            for (int c = 0; c < 2; c++)
#pragma unroll
                for (int r = 0; r < 4; r++) {
                    int row = et * 64 + rl0 + t2 * 16 + lk * 4 + r;
                    int col = colb + c * 16 + lrow;
                    WMBp[row * 128 + col] = f2bf(acc[t2][c][r]);
                }
    }
    // ---- tb bias GEMV from LDS Mt ----
    if (t < 64) {
        const int rl = t;
        const int sw = (rl & 7) << 3;
        float s = 0.f;
#pragma unroll 4
        for (int j = 0; j < 32; j++) {
            bf16x8 ch = *(const bf16x8*)(Mt + rl * 256 + ((j * 8) ^ sw));
#pragma unroll
            for (int u = 0; u < 8; u++) s += bl[j * 8 + u] * bf2f((unsigned short)ch[u]);
        }
        ws[OFF_TB + b * DOUT + et * 64 + rl] = s + btc[et * 64 + rl];
    }
}

#define LDP 136

// BN-stats GEMM: recompute tt = x @ WM^T + tb, reduce rows to (s1,s2), write
// atomic-free partials part[b][n]. grid (32 b, 32 nt), 256 thr.
__global__ __launch_bounds__(256) void kS(const float* __restrict__ x,
                                          float* __restrict__ ws) {
    const int t = threadIdx.x;
    const int wid = t >> 6, l = t & 63;
    const int b = blockIdx.x, nt = blockIdx.y;
    const int n0 = nt * 64;
    const int lrow = l & 15, lk = l >> 4;
    __shared__ unsigned short xs[64 * LDP];
    __shared__ float sp1[4][64], sp2[4][64];

    const float4* xg = (const float4*)(x + (size_t)(b * NN + n0) * DIN);
#pragma unroll
    for (int it = 0; it < 8; it++) {
        int idx = it * 256 + t;
        int row = idx >> 5, kq = idx & 31;
        float4 v = xg[idx];
        ushort4 u;
        u.x = f2bf(v.x); u.y = f2bf(v.y); u.z = f2bf(v.z); u.w = f2bf(v.w);
        *(ushort4*)(xs + row * LDP + kq * 4) = u;
    }
    __syncthreads();

    const int colbase = wid * 64;
    f32x4 acc[4][4];
#pragma unroll
    for (int rt = 0; rt < 4; rt++)
#pragma unroll
        for (int ct = 0; ct < 4; ct++) acc[rt][ct] = (f32x4){0.f, 0.f, 0.f, 0.f};
    {
        const unsigned short* wb = (const unsigned short*)(ws + OFF_WMB) + (size_t)b * 32768u;
#pragma unroll
        for (int kk = 0; kk < 4; kk++) {
            int ko = kk * 32 + lk * 8;
            bf16x8 a[4];
#pragma unroll
            for (int rt = 0; rt < 4; rt++)
                a[rt] = *(const bf16x8*)(xs + (rt * 16 + lrow) * LDP + ko);
            bf16x8 bf[4];
#pragma unroll
            for (int ct = 0; ct < 4; ct++)
                bf[ct] = *(const bf16x8*)(wb + (size_t)(colbase + ct * 16 + lrow) * DIN + ko);
#pragma unroll
            for (int rt = 0; rt < 4; rt++)
#pragma unroll
                for (int ct = 0; ct < 4; ct++)
                    acc[rt][ct] = __builtin_amdgcn_mfma_f32_16x16x32_bf16(a[rt], bf[ct], acc[rt][ct], 0, 0, 0);
        }
#pragma unroll
        for (int ct = 0; ct < 4; ct++) {
            float bv = ws[OFF_TB + b * DOUT + colbase + ct * 16 + lrow];
#pragma unroll
            for (int rt = 0; rt < 4; rt++)
#pragma unroll
                for (int r = 0; r < 4; r++) acc[rt][ct][r] += bv;
        }
    }

    float s1[4][4], s2[4][4];
#pragma unroll
    for (int rt = 0; rt < 4; rt++)
#pragma unroll
        for (int r = 0; r < 4; r++) { s1[rt][r] = 0.f; s2[rt][r] = 0.f; }
#pragma unroll
    for (int rt = 0; rt < 4; rt++)
#pragma unroll
        for (int ct = 0; ct < 4; ct++)
#pragma unroll
            for (int r = 0; r < 4; r++) {
                float v = acc[rt][ct][r];
                s1[rt][r] += v; s2[rt][r] += v * v;
            }
#pragma unroll
    for (int off = 1; off < 16; off <<= 1) {
#pragma unroll
        for (int rt = 0; rt < 4; rt++)
#pragma unroll
            for (int r = 0; r < 4; r++) {
                s1[rt][r] += __shfl_xor(s1[rt][r], off, 64);
                s2[rt][r] += __shfl_xor(s2[rt][r], off, 64);
            }
    }
    if (lrow == 0) {
#pragma unroll
        for (int rt = 0; rt < 4; rt++)
#pragma unroll
            for (int r = 0; r < 4; r++) {
                int nidx = rt * 16 + lk * 4 + r;
                sp1[wid][nidx] = s1[rt][r];
                sp2[wid][nidx] = s2[rt][r];
            }
    }
    __syncthreads();
    if (t < 64) {
        float S1 = sp1[0][t] + sp1[1][t] + sp1[2][t] + sp1[3][t];
        float S2 = sp2[0][t] + sp2[1][t] + sp2[2][t] + sp2[3][t];
        ws[OFF_P1 + (size_t)b * NN + n0 + t] = S1;
        ws[OFF_P2 + (size_t)b * NN + n0 + t] = S2;
    }
}

// Fused dual-GEMM + BN finalize + epilogue, 64-row tiles. tt and x1 in registers;
// BN finalize from L2-hot partials overlapped with x staging; shared a-frags feed
// both weight sets. grid (32 b, 32 nt).
__global__ __launch_bounds__(256, 2) void kF(const float* __restrict__ x,
                                             const float* __restrict__ bl,
                                             const float* __restrict__ gamma,
                                             const float* __restrict__ beta,
                                             float* __restrict__ out,
                                             float* __restrict__ ws) {
    const int t = threadIdx.x;
    const int wid = t >> 6, l = t & 63;
    const int b = blockIdx.x;
    const int nt = blockIdx.y;
    const int n0 = nt * 64;
    const int lrow = l & 15, lk = l >> 4;
    __shared__ unsigned short xs[64 * LDP];
    __shared__ float scs[64], shs[64];

    // issue x loads first; BN finalize overlaps their latency
    const float4* xg = (const float4*)(x + (size_t)(b * NN + n0) * DIN);
    float4 xv[8];
#pragma unroll
    for (int it = 0; it < 8; it++) xv[it] = xg[it * 256 + t];

    if (t < 64) {
        float S1 = 0.f, S2 = 0.f;
#pragma unroll 8
        for (int b2 = 0; b2 < BB; b2++) {
            S1 += ws[OFF_P1 + (size_t)b2 * NN + n0 + t];
            S2 += ws[OFF_P2 + (size_t)b2 * NN + n0 + t];
        }
        float mean = S1 * (1.f / 8192.f);
        float var  = S2 * (1.f / 8192.f) - mean * mean;
        float sc = gamma[n0 + t] * rsqrtf(fmaxf(var, 0.f) + 1e-5f);
        scs[t] = sc;
        shs[t] = beta[n0 + t] - mean * sc;
    }
#pragma unroll
    for (int it = 0; it < 8; it++) {
        int idx = it * 256 + t;
        int row = idx >> 5, kq = idx & 31;
        ushort4 u;
        u.x = f2bf(xv[it].x); u.y = f2bf(xv[it].y); u.z = f2bf(xv[it].z); u.w = f2bf(xv[it].w);
        *(ushort4*)(xs + row * LDP + kq * 4) = u;
    }
    __syncthreads();

    const int colbase = wid * 64;

    // ---- fused dual GEMM over 64 rows: acc = x@WM^T (tt), acc0 = x@Wl^T (x1) ----
    f32x4 acc[4][4], acc0[4][4];
#pragma unroll
    for (int rt = 0; rt < 4; rt++)
#pragma unroll
        for (int ct = 0; ct < 4; ct++) {
            acc[rt][ct]  = (f32x4){0.f, 0.f, 0.f, 0.f};
            acc0[rt][ct] = (f32x4){0.f, 0.f, 0.f, 0.f};
        }
    {
        const unsigned short* wbM = (const unsigned short*)(ws + OFF_WMB) + (size_t)b * 32768u;
        const unsigned short* wbL = (const unsigned short*)(ws + OFF_WLB);
#pragma unroll
        for (int kk = 0; kk < 4; kk++) {
            int ko = kk * 32 + lk * 8;
            bf16x8 a[4];
#pragma unroll
            for (int rt = 0; rt < 4; rt++)
                a[rt] = *(const bf16x8*)(xs + (rt * 16 + lrow) * LDP + ko);
            bf16x8 bf[4];
#pragma unroll
            for (int ct = 0; ct < 4; ct++)
                bf[ct] = *(const bf16x8*)(wbM + (size_t)(colbase + ct * 16 + lrow) * DIN + ko);
#pragma unroll
            for (int rt = 0; rt < 4; rt++)
#pragma unroll
                for (int ct = 0; ct < 4; ct++)
                    acc[rt][ct] = __builtin_amdgcn_mfma_f32_16x16x32_bf16(a[rt], bf[ct], acc[rt][ct], 0, 0, 0);
#pragma unroll
            for (int ct = 0; ct < 4; ct++)
                bf[ct] = *(const bf16x8*)(wbL + (size_t)(colbase + ct * 16 + lrow) * DIN + ko);
#pragma unroll
            for (int rt = 0; rt < 4; rt++)
#pragma unroll
                for (int ct = 0; ct < 4; ct++)
                    acc0[rt][ct] = __builtin_amdgcn_mfma_f32_16x16x32_bf16(a[rt], bf[ct], acc0[rt][ct], 0, 0, 0);
        }
#pragma unroll
        for (int ct = 0; ct < 4; ct++) {
            float bvM = ws[OFF_TB + b * DOUT + colbase + ct * 16 + lrow];
            float bvL = bl[colbase + ct * 16 + lrow];
#pragma unroll
            for (int rt = 0; rt < 4; rt++)
#pragma unroll
                for (int r = 0; r < 4; r++) {
                    acc[rt][ct][r]  += bvM;
                    acc0[rt][ct][r] += bvL;
                }
        }
    }

    // ---- epilogue straight from registers: out = (x1 + relu(bn(tt)))*g + hb ----
    float gv[4], hbv[4];
#pragma unroll
    for (int ct = 0; ct < 4; ct++) {
        int o = colbase + ct * 16 + lrow;
        gv[ct]  = ws[OFF_G  + b * DOUT + o];
        hbv[ct] = ws[OFF_HB + b * DOUT + o];
    }
#pragma unroll
    for (int rt = 0; rt < 4; rt++)
#pragma unroll
        for (int r = 0; r < 4; r++) {
            int nidx = rt * 16 + lk * 4 + r;
            float sc = scs[nidx], sh = shs[nidx];
            int n = n0 + nidx;
#pragma unroll
            for (int ct = 0; ct < 4; ct++) {
                int o = colbase + ct * 16 + lrow;
                float rv = fmaxf(acc[rt][ct][r] * sc + sh, 0.f);
                out[(size_t)((b * NN + n) * DOUT) + o] = (acc0[rt][ct][r] + rv) * gv[ct] + hbv[ct];
            }
        }
}

extern "C" void kernel_launch(void* const* d_in, const int* in_sizes, int n_in,
                              void* d_out, int out_size, void* d_ws, size_t ws_size,
                              hipStream_t stream) {
    const float* ctx   = (const float*)d_in[0];
    const float* x     = (const float*)d_in[1];
    const float* Wl    = (const float*)d_in[2];
    const float* bl    = (const float*)d_in[3];
    const float* Whb   = (const float*)d_in[4];
    const float* Wg    = (const float*)d_in[5];
    const float* bg    = (const float*)d_in[6];
    const float* Wk    = (const float*)d_in[7];
    const float* Wv    = (const float*)d_in[8];
    const float* Wtc   = (const float*)d_in[9];
    const float* btc   = (const float*)d_in[10];
    const float* gamma = (const float*)d_in[11];
    const float* beta  = (const float*)d_in[12];
    float* out = (float*)d_out;
    float* ws  = (float*)d_ws;

    kXW <<<10, 256, 0, stream>>>(Wl, Wtc, ws);
    kP  <<<BB, 1024, 0, stream>>>(ctx, bg, Wk, Wv, Wg, Whb, ws);
    k45 <<<dim3(4, BB), 512, 0, stream>>>(bl, btc, ws);
    kS  <<<dim3(BB, 32), 256, 0, stream>>>(x, ws);
    kF  <<<dim3(BB, 32), 256, 0, stream>>>(x, bl, gamma, beta, out, ws);
}

// Round 8
// 208.747 us; speedup vs baseline: 1.3014x; 1.1361x over previous
//
#include <hip/hip_runtime.h>
#include <hip/hip_bf16.h>

#define BB   32
#define NN   2048
#define DIN  128
#define DOUT 256
#define DCTX 259

// ---- workspace layout (float-slot offsets) ----
#define OFF_AB   0u          // A  bf16 [B][256][256] (dead before kF)
#define OFF_WMB  16777216u   // WM bf16 [B][256 e][128 i] = 524288
#define OFF_WLB  17301504u   // W_layer bf16 [256 o][128 i] = 16384
#define OFF_WLTB 17317888u   // W_layer^T bf16 [128 i][256 o] = 16384
#define OFF_WTCB 17334272u   // W_tc bf16 [256 e][256 o] = 32768
#define OFF_G    17367040u
#define OFF_HB   17375232u
#define OFF_TB   17383424u
#define OFF_P1   17655296u   // BN partial s1 [32 b][2048 n] fp32
#define OFF_P2   17720832u   // BN partial s2 [32 b][2048 n] fp32
#define OFF_KS   17786368u   // ks fp32 [32 b][256]
#define OFF_VS   17794560u   // vs fp32 [32 b][256]
// end 17802752 slots ≈ 71.2 MB

typedef short bf16x8 __attribute__((ext_vector_type(8)));
typedef float f32x4  __attribute__((ext_vector_type(4)));

static __device__ inline unsigned short f2bf(float f) {
    __hip_bfloat16 h = __float2bfloat16(f);
    return *(unsigned short*)&h;
}
static __device__ inline float bf2f(unsigned short u) {
    unsigned v = ((unsigned)u) << 16;
    float f;
    __builtin_memcpy(&f, &v, 4);
    return f;
}

// Merged pack + ctx-GEMV. Blocks 0..9: bf16 weight packing. Blocks 10..73:
// GEMV tiles (4 matrices x 16 row-tiles of 16), LDS-staged fully coalesced:
// ctx[32][260] + W-tile[16][260] -> per-thread LDS dots (no global gathers).
__global__ __launch_bounds__(256) void kW(const float* __restrict__ Wl,
                                          const float* __restrict__ Wtc,
                                          const float* __restrict__ Wk,
                                          const float* __restrict__ Wv,
                                          const float* __restrict__ Wg,
                                          const float* __restrict__ Whb,
                                          const float* __restrict__ ctx,
                                          const float* __restrict__ bg,
                                          float* __restrict__ ws) {
    const unsigned bb = blockIdx.x, t = threadIdx.x;
    __shared__ float ctxs[32][260];
    __shared__ float wt[16][260];

    if (bb < 8u) {
        unsigned base = bb * 8192u;
        unsigned short* dst = (unsigned short*)(ws + OFF_WTCB);
#pragma unroll
        for (int j = 0; j < 32; j++) {
            unsigned i = base + (unsigned)j * 256u + t;
            dst[i] = f2bf(Wtc[i]);
        }
        return;
    } else if (bb == 8u) {
        unsigned short* dst = (unsigned short*)(ws + OFF_WLTB);   // [i][o]
        for (unsigned idx = t; idx < 32768u; idx += 256u) {
            unsigned i = idx >> 8, o = idx & 255u;
            dst[idx] = f2bf(Wl[o * 128u + i]);
        }
        return;
    } else if (bb == 9u) {
        unsigned short* dst = (unsigned short*)(ws + OFF_WLB);    // [o][i]
        for (unsigned idx = t; idx < 32768u; idx += 256u) dst[idx] = f2bf(Wl[idx]);
        return;
    }

    // ---- GEMV tile block ----
    const int j = bb - 10;            // 0..63
    const int m = j >> 4;             // matrix select
    const int o0 = (j & 15) * 16;
    const float* Wm; int C;
    if (m == 0)      { Wm = Wk;  C = 256; }
    else if (m == 1) { Wm = Wv;  C = 256; }
    else if (m == 2) { Wm = Wg;  C = DCTX; }
    else             { Wm = Whb; C = DCTX; }

    for (int i = t; i < 32 * 260; i += 256) {
        int b2 = i / 260, c = i - b2 * 260;
        ctxs[b2][c] = (c < DCTX) ? ctx[b2 * DCTX + c] : 0.f;
    }
    for (int i = t; i < 16 * C; i += 256) {
        int r = i / C, c = i - r * C;
        wt[r][c] = Wm[(size_t)(o0 + r) * C + c];
    }
    __syncthreads();

    const int ol = t & 15, b2 = t >> 4;       // each thread: 2 batches
    float s0 = 0.f, s1 = 0.f;
#pragma unroll 8
    for (int c = 0; c < C; c++) {
        float w = wt[ol][c];
        s0 += w * ctxs[b2][c];
        s1 += w * ctxs[b2 + 16][c];
    }
    const int o = o0 + ol;
    if (m == 0) {
        ws[OFF_KS + b2 * DOUT + o] = s0;
        ws[OFF_KS + (b2 + 16) * DOUT + o] = s1;
    } else if (m == 1) {
        ws[OFF_VS + b2 * DOUT + o] = s0;
        ws[OFF_VS + (b2 + 16) * DOUT + o] = s1;
    } else if (m == 2) {
        float bgo = bg[o];
        ws[OFF_G + b2 * DOUT + o] = 1.f / (1.f + __expf(-(s0 + bgo)));
        ws[OFF_G + (b2 + 16) * DOUT + o] = 1.f / (1.f + __expf(-(s1 + bgo)));
    } else {
        ws[OFF_HB + b2 * DOUT + o] = s0;
        ws[OFF_HB + (b2 + 16) * DOUT + o] = s1;
    }
}

// Softmax + A only (GEMV moved to kW). 1024 threads, grid B.
__global__ __launch_bounds__(1024) void kP(float* __restrict__ ws) {
    const int b = blockIdx.x, t = threadIdx.x;
    const int o = t & 255, q = t >> 8;
    __shared__ __align__(16) float ks[256], vs[256], rms[256], ris[256];
    __shared__ float pm[1024], ps[1024];
    if (t < 256)            ks[t] = ws[OFF_KS + b * DOUT + t];
    else if (t < 512)       vs[t - 256] = ws[OFF_VS + b * DOUT + (t - 256)];
    __syncthreads();

    const float ko = ks[o];
    const float4* vs4 = (const float4*)vs;
    float pmax = -1e30f;
#pragma unroll 4
    for (int j = q * 16; j < q * 16 + 16; j++) {
        float4 v = vs4[j];
        pmax = fmaxf(pmax, fmaxf(fmaxf(ko * v.x, ko * v.y), fmaxf(ko * v.z, ko * v.w)));
    }
    pm[q * 256 + o] = pmax;
    __syncthreads();
    float m = fmaxf(fmaxf(pm[o], pm[256 + o]), fmaxf(pm[512 + o], pm[768 + o]));
    float psum = 0.f;
#pragma unroll 4
    for (int j = q * 16; j < q * 16 + 16; j++) {
        float4 v = vs4[j];
        psum += __expf(ko * v.x - m) + __expf(ko * v.y - m)
              + __expf(ko * v.z - m) + __expf(ko * v.w - m);
    }
    ps[q * 256 + o] = psum;
    __syncthreads();
    float ri = 1.f / (ps[o] + ps[256 + o] + ps[512 + o] + ps[768 + o]);
    if (q == 0) { rms[o] = m; ris[o] = ri; }
    __syncthreads();

    const float ve = vs[o];
    float cp = 0.f;
#pragma unroll 4
    for (int o2 = q * 64; o2 < q * 64 + 64; o2++)
        cp += __expf(ks[o2] * ve - rms[o2]) * ris[o2];
    pm[q * 256 + o] = cp;
    __syncthreads();
    float ci = 1.f / (1e-9f + pm[o] + pm[256 + o] + pm[512 + o] + pm[768 + o]);
    unsigned short* Ab = (unsigned short*)(ws + OFF_AB) + (size_t)b * 65536u;
#pragma unroll 4
    for (int o2 = q * 64; o2 < q * 64 + 64; o2++) {
        float a = __expf(ks[o2] * ve - rms[o2]) * ris[o2] * ci;
        Ab[o2 * 256 + o] = f2bf(a);
    }
}

// Fused k4m+k5m, 64-row et-quarters. Mt in LDS (XOR-swizzled), then
// WM = Mt @ Wl^T and tb GEMV. grid (4 e-quarters, B), 512 threads.
__global__ __launch_bounds__(512) void k45(const float* __restrict__ bl,
                                           const float* __restrict__ btc,
                                           float* __restrict__ ws) {
    const int t = threadIdx.x, wid = t >> 6, l = t & 63;
    const int b = blockIdx.y, et = blockIdx.x;
    const int lrow = l & 15, lk = l >> 4;
    __shared__ unsigned short Mt[64 * 256];   // 32 KB, swizzled: col ^ ((row&7)<<3)
    const unsigned short* Wtcb = (const unsigned short*)(ws + OFF_WTCB);

    // ---- phase A: Mt rows [et*64, et*64+64), waves 2 rows x 4 cols ----
    {
        const unsigned short* Ab = (const unsigned short*)(ws + OFF_AB) + (size_t)b * 65536u;
        const int w_r = wid >> 2, w_c = wid & 3;
        const int rbase = et * 64 + w_r * 32;
        const int colbase = w_c * 64;
        f32x4 acc[2][4];
#pragma unroll
        for (int i = 0; i < 2; i++)
#pragma unroll
            for (int c = 0; c < 4; c++) acc[i][c] = (f32x4){0.f, 0.f, 0.f, 0.f};
        const unsigned short* ar0 = Wtcb + (rbase + lrow) * 256;
#pragma unroll
        for (int kk = 0; kk < 8; kk++) {
            int ko = kk * 32 + lk * 8;
            bf16x8 a0 = *(const bf16x8*)(ar0 + ko);
            bf16x8 a1 = *(const bf16x8*)(ar0 + 16 * 256 + ko);
            bf16x8 bfr[4];
#pragma unroll
            for (int c = 0; c < 4; c++)
                bfr[c] = *(const bf16x8*)(Ab + (colbase + c * 16 + lrow) * 256 + ko);
#pragma unroll
            for (int c = 0; c < 4; c++) {
                acc[0][c] = __builtin_amdgcn_mfma_f32_16x16x32_bf16(a0, bfr[c], acc[0][c], 0, 0, 0);
                acc[1][c] = __builtin_amdgcn_mfma_f32_16x16x32_bf16(a1, bfr[c], acc[1][c], 0, 0, 0);
            }
        }
#pragma unroll
        for (int t2 = 0; t2 < 2; t2++)
#pragma unroll
            for (int c = 0; c < 4; c++)
#pragma unroll
                for (int r = 0; r < 4; r++) {
                    int grow = rbase + t2 * 16 + lk * 4 + r;
                    int col = colbase + c * 16 + lrow;
                    float idv = bf2f(Wtcb[grow * 256 + col]);
                    int rl = grow - et * 64;
                    Mt[rl * 256 + (col ^ ((rl & 7) << 3))] = f2bf(idv - acc[t2][c][r]);
                }
    }
    __syncthreads();
    // ---- phase B: WM rows [et*64..+64) = Mt @ Wl^T ----
    {
        const unsigned short* Wltb = (const unsigned short*)(ws + OFF_WLTB);
        const int w_r = wid >> 2, w_c = wid & 3;
        const int rl0 = w_r * 32;
        const int colb = w_c * 32;
        f32x4 acc[2][2];
#pragma unroll
        for (int i = 0; i < 2; i++)
#pragma unroll
            for (int c = 0; c < 2; c++) acc[i][c] = (f32x4){0.f, 0.f, 0.f, 0.f};
        const int arow0 = rl0 + lrow, arow1 = rl0 + 16 + lrow;
        const int asw0 = (arow0 & 7) << 3, asw1 = (arow1 & 7) << 3;
#pragma unroll
        for (int kk = 0; kk < 8; kk++) {
            int ko = kk * 32 + lk * 8;
            bf16x8 a0 = *(const bf16x8*)(Mt + arow0 * 256 + (ko ^ asw0));
            bf16x8 a1 = *(const bf16x8*)(Mt + arow1 * 256 + (ko ^ asw1));
            bf16x8 bfr[2];
#pragma unroll
            for (int c = 0; c < 2; c++)
                bfr[c] = *(const bf16x8*)(Wltb + (colb + c * 16 + lrow) * 256 + ko);
#pragma unroll
            for (int c = 0; c < 2; c++) {
                acc[0][c] = __builtin_amdgcn_mfma_f32_16x16x32_bf16(a0, bfr[c], acc[0][c], 0, 0, 0);
                acc[1][c] = __builtin_amdgcn_mfma_f32_16x16x32_bf16(a1, bfr[c], acc[1][c], 0, 0, 0);
            }
        }
        unsigned short* WMBp = (unsigned short*)(ws + OFF_WMB) + (size_t)b * 32768u;
#pragma unroll
        for (int t2 = 0; t2 < 2; t2++)
#pragma unroll
            for (int c = 0; c < 2; c++)
#pragma unroll
                for (int r = 0; r < 4; r++) {
                    int row = et * 64 + rl0 + t2 * 16 + lk * 4 + r;
                    int col = colb + c * 16 + lrow;
                    WMBp[row * 128 + col] = f2bf(acc[t2][c][r]);
                }
    }
    // ---- tb bias GEMV from LDS Mt ----
    if (t < 64) {
        const int rl = t;
        const int sw = (rl & 7) << 3;
        float s = 0.f;
#pragma unroll 4
        for (int j = 0; j < 32; j++) {
            bf16x8 ch = *(const bf16x8*)(Mt + rl * 256 + ((j * 8) ^ sw));
#pragma unroll
            for (int u = 0; u < 8; u++) s += bl[j * 8 + u] * bf2f((unsigned short)ch[u]);
        }
        ws[OFF_TB + b * DOUT + et * 64 + rl] = s + btc[et * 64 + rl];
    }
}

#define LDP 136

// BN-stats GEMM: recompute tt = x @ WM^T + tb, reduce rows to (s1,s2), write
// atomic-free partials part[b][n]. grid (32 b, 32 nt), 256 thr.
__global__ __launch_bounds__(256) void kS(const float* __restrict__ x,
                                          float* __restrict__ ws) {
    const int t = threadIdx.x;
    const int wid = t >> 6, l = t & 63;
    const int b = blockIdx.x, nt = blockIdx.y;
    const int n0 = nt * 64;
    const int lrow = l & 15, lk = l >> 4;
    __shared__ unsigned short xs[64 * LDP];
    __shared__ float sp1[4][64], sp2[4][64];

    const float4* xg = (const float4*)(x + (size_t)(b * NN + n0) * DIN);
#pragma unroll
    for (int it = 0; it < 8; it++) {
        int idx = it * 256 + t;
        int row = idx >> 5, kq = idx & 31;
        float4 v = xg[idx];
        ushort4 u;
        u.x = f2bf(v.x); u.y = f2bf(v.y); u.z = f2bf(v.z); u.w = f2bf(v.w);
        *(ushort4*)(xs + row * LDP + kq * 4) = u;
    }
    __syncthreads();

    const int colbase = wid * 64;
    f32x4 acc[4][4];
#pragma unroll
    for (int rt = 0; rt < 4; rt++)
#pragma unroll
        for (int ct = 0; ct < 4; ct++) acc[rt][ct] = (f32x4){0.f, 0.f, 0.f, 0.f};
    {
        const unsigned short* wb = (const unsigned short*)(ws + OFF_WMB) + (size_t)b * 32768u;
#pragma unroll
        for (int kk = 0; kk < 4; kk++) {
            int ko = kk * 32 + lk * 8;
            bf16x8 a[4];
#pragma unroll
            for (int rt = 0; rt < 4; rt++)
                a[rt] = *(const bf16x8*)(xs + (rt * 16 + lrow) * LDP + ko);
            bf16x8 bf[4];
#pragma unroll
            for (int ct = 0; ct < 4; ct++)
                bf[ct] = *(const bf16x8*)(wb + (size_t)(colbase + ct * 16 + lrow) * DIN + ko);
#pragma unroll
            for (int rt = 0; rt < 4; rt++)
#pragma unroll
                for (int ct = 0; ct < 4; ct++)
                    acc[rt][ct] = __builtin_amdgcn_mfma_f32_16x16x32_bf16(a[rt], bf[ct], acc[rt][ct], 0, 0, 0);
        }
#pragma unroll
        for (int ct = 0; ct < 4; ct++) {
            float bv = ws[OFF_TB + b * DOUT + colbase + ct * 16 + lrow];
#pragma unroll
            for (int rt = 0; rt < 4; rt++)
#pragma unroll
                for (int r = 0; r < 4; r++) acc[rt][ct][r] += bv;
        }
    }

    float s1[4][4], s2[4][4];
#pragma unroll
    for (int rt = 0; rt < 4; rt++)
#pragma unroll
        for (int r = 0; r < 4; r++) { s1[rt][r] = 0.f; s2[rt][r] = 0.f; }
#pragma unroll
    for (int rt = 0; rt < 4; rt++)
#pragma unroll
        for (int ct = 0; ct < 4; ct++)
#pragma unroll
            for (int r = 0; r < 4; r++) {
                float v = acc[rt][ct][r];
                s1[rt][r] += v; s2[rt][r] += v * v;
            }
#pragma unroll
    for (int off = 1; off < 16; off <<= 1) {
#pragma unroll
        for (int rt = 0; rt < 4; rt++)
#pragma unroll
            for (int r = 0; r < 4; r++) {
                s1[rt][r] += __shfl_xor(s1[rt][r], off, 64);
                s2[rt][r] += __shfl_xor(s2[rt][r], off, 64);
            }
    }
    if (lrow == 0) {
#pragma unroll
        for (int rt = 0; rt < 4; rt++)
#pragma unroll
            for (int r = 0; r < 4; r++) {
                int nidx = rt * 16 + lk * 4 + r;
                sp1[wid][nidx] = s1[rt][r];
                sp2[wid][nidx] = s2[rt][r];
            }
    }
    __syncthreads();
    if (t < 64) {
        float S1 = sp1[0][t] + sp1[1][t] + sp1[2][t] + sp1[3][t];
        float S2 = sp2[0][t] + sp2[1][t] + sp2[2][t] + sp2[3][t];
        ws[OFF_P1 + (size_t)b * NN + n0 + t] = S1;
        ws[OFF_P2 + (size_t)b * NN + n0 + t] = S2;
    }
}

// Fused dual-GEMM + BN finalize + epilogue, 64-row tiles. NO VGPR cap (the
// (256,2) cap forced accumulator spills: acc+acc0 alone = 128 VGPR). BN
// partial fold spread over 256 threads. grid (32 b, 32 nt).
__global__ __launch_bounds__(256) void kF(const float* __restrict__ x,
                                          const float* __restrict__ bl,
                                          const float* __restrict__ gamma,
                                          const float* __restrict__ beta,
                                          float* __restrict__ out,
                                          float* __restrict__ ws) {
    const int t = threadIdx.x;
    const int wid = t >> 6, l = t & 63;
    const int b = blockIdx.x;
    const int nt = blockIdx.y;
    const int n0 = nt * 64;
    const int lrow = l & 15, lk = l >> 4;
    __shared__ unsigned short xs[64 * LDP];
    __shared__ float sq1[4][64], sq2[4][64];
    __shared__ float scs[64], shs[64];

    // issue x loads first; BN partial fold overlaps their latency
    const float4* xg = (const float4*)(x + (size_t)(b * NN + n0) * DIN);
    float4 xv[8];
#pragma unroll
    for (int it = 0; it < 8; it++) xv[it] = xg[it * 256 + t];

    {
        int n = t & 63, g = t >> 6;          // 4 groups x 8 batches
        float S1 = 0.f, S2 = 0.f;
#pragma unroll
        for (int b2 = g * 8; b2 < g * 8 + 8; b2++) {
            S1 += ws[OFF_P1 + (size_t)b2 * NN + n0 + n];
            S2 += ws[OFF_P2 + (size_t)b2 * NN + n0 + n];
        }
        sq1[g][n] = S1; sq2[g][n] = S2;
    }
    __syncthreads();
    if (t < 64) {
        float S1 = sq1[0][t] + sq1[1][t] + sq1[2][t] + sq1[3][t];
        float S2 = sq2[0][t] + sq2[1][t] + sq2[2][t] + sq2[3][t];
        float mean = S1 * (1.f / 8192.f);
        float var  = S2 * (1.f / 8192.f) - mean * mean;
        float sc = gamma[n0 + t] * rsqrtf(fmaxf(var, 0.f) + 1e-5f);
        scs[t] = sc;
        shs[t] = beta[n0 + t] - mean * sc;
    }
#pragma unroll
    for (int it = 0; it < 8; it++) {
        int idx = it * 256 + t;
        int row = idx >> 5, kq = idx & 31;
        ushort4 u;
        u.x = f2bf(xv[it].x); u.y = f2bf(xv[it].y); u.z = f2bf(xv[it].z); u.w = f2bf(xv[it].w);
        *(ushort4*)(xs + row * LDP + kq * 4) = u;
    }
    __syncthreads();

    const int colbase = wid * 64;

    // ---- fused dual GEMM over 64 rows: acc = x@WM^T (tt), acc0 = x@Wl^T (x1) ----
    f32x4 acc[4][4], acc0[4][4];
#pragma unroll
    for (int rt = 0; rt < 4; rt++)
#pragma unroll
        for (int ct = 0; ct < 4; ct++) {
            acc[rt][ct]  = (f32x4){0.f, 0.f, 0.f, 0.f};
            acc0[rt][ct] = (f32x4){0.f, 0.f, 0.f, 0.f};
        }
    {
        const unsigned short* wbM = (const unsigned short*)(ws + OFF_WMB) + (size_t)b * 32768u;
        const unsigned short* wbL = (const unsigned short*)(ws + OFF_WLB);
#pragma unroll
        for (int kk = 0; kk < 4; kk++) {
            int ko = kk * 32 + lk * 8;
            bf16x8 a[4];
#pragma unroll
            for (int rt = 0; rt < 4; rt++)
                a[rt] = *(const bf16x8*)(xs + (rt * 16 + lrow) * LDP + ko);
            bf16x8 bf[4];
#pragma unroll
            for (int ct = 0; ct < 4; ct++)
                bf[ct] = *(const bf16x8*)(wbM + (size_t)(colbase + ct * 16 + lrow) * DIN + ko);
#pragma unroll
            for (int rt = 0; rt < 4; rt++)
#pragma unroll
                for (int ct = 0; ct < 4; ct++)
                    acc[rt][ct] = __builtin_amdgcn_mfma_f32_16x16x32_bf16(a[rt], bf[ct], acc[rt][ct], 0, 0, 0);
#pragma unroll
            for (int ct = 0; ct < 4; ct++)
                bf[ct] = *(const bf16x8*)(wbL + (size_t)(colbase + ct * 16 + lrow) * DIN + ko);
#pragma unroll
            for (int rt = 0; rt < 4; rt++)
#pragma unroll
                for (int ct = 0; ct < 4; ct++)
                    acc0[rt][ct] = __builtin_amdgcn_mfma_f32_16x16x32_bf16(a[rt], bf[ct], acc0[rt][ct], 0, 0, 0);
        }
#pragma unroll
        for (int ct = 0; ct < 4; ct++) {
            float bvM = ws[OFF_TB + b * DOUT + colbase + ct * 16 + lrow];
            float bvL = bl[colbase + ct * 16 + lrow];
#pragma unroll
            for (int rt = 0; rt < 4; rt++)
#pragma unroll
                for (int r = 0; r < 4; r++) {
                    acc[rt][ct][r]  += bvM;
                    acc0[rt][ct][r] += bvL;
                }
        }
    }

    // ---- epilogue straight from registers: out = (x1 + relu(bn(tt)))*g + hb ----
    float gv[4], hbv[4];
#pragma unroll
    for (int ct = 0; ct < 4; ct++) {
        int o = colbase + ct * 16 + lrow;
        gv[ct]  = ws[OFF_G  + b * DOUT + o];
        hbv[ct] = ws[OFF_HB + b * DOUT + o];
    }
#pragma unroll
    for (int rt = 0; rt < 4; rt++)
#pragma unroll
        for (int r = 0; r < 4; r++) {
            int nidx = rt * 16 + lk * 4 + r;
            float sc = scs[nidx], sh = shs[nidx];
            int n = n0 + nidx;
#pragma unroll
            for (int ct = 0; ct < 4; ct++) {
                int o = colbase + ct * 16 + lrow;
                float rv = fmaxf(acc[rt][ct][r] * sc + sh, 0.f);
                out[(size_t)((b * NN + n) * DOUT) + o] = (acc0[rt][ct][r] + rv) * gv[ct] + hbv[ct];
            }
        }
}

extern "C" void kernel_launch(void* const* d_in, const int* in_sizes, int n_in,
                              void* d_out, int out_size, void* d_ws, size_t ws_size,
                              hipStream_t stream) {
    const float* ctx   = (const float*)d_in[0];
    const float* x     = (const float*)d_in[1];
    const float* Wl    = (const float*)d_in[2];
    const float* bl    = (const float*)d_in[3];
    const float* Whb   = (const float*)d_in[4];
    const float* Wg    = (const float*)d_in[5];
    const float* bg    = (const float*)d_in[6];
    const float* Wk    = (const float*)d_in[7];
    const float* Wv    = (const float*)d_in[8];
    const float* Wtc   = (const float*)d_in[9];
    const float* btc   = (const float*)d_in[10];
    const float* gamma = (const float*)d_in[11];
    const float* beta  = (const float*)d_in[12];
    float* out = (float*)d_out;
    float* ws  = (float*)d_ws;

    kW  <<<74, 256, 0, stream>>>(Wl, Wtc, Wk, Wv, Wg, Whb, ctx, bg, ws);
    kP  <<<BB, 1024, 0, stream>>>(ws);
    k45 <<<dim3(4, BB), 512, 0, stream>>>(bl, btc, ws);
    kS  <<<dim3(BB, 32), 256, 0, stream>>>(x, ws);
    kF  <<<dim3(BB, 32), 256, 0, stream>>>(x, bl, gamma, beta, out, ws);
}

// Round 9
// 207.979 us; speedup vs baseline: 1.3062x; 1.0037x over previous
//
#include <hip/hip_runtime.h>
#include <hip/hip_bf16.h>

#define BB   32
#define NN   2048
#define DIN  128
#define DOUT 256
#define DCTX 259

// ---- workspace layout (float-slot offsets) ----
#define OFF_AB   0u          // A  bf16 [B][256][256] (dead before kFS)
#define OFF_WMB  16777216u   // WM bf16 [B][256 e][128 i] = 524288
#define OFF_WLB  17301504u   // W_layer bf16 [256 o][128 i] = 16384
#define OFF_WLTB 17317888u   // W_layer^T bf16 [128 i][256 o] = 16384
#define OFF_WTCB 17334272u   // W_tc bf16 [256 e][256 o] = 32768
#define OFF_G    17367040u
#define OFF_HB   17375232u
#define OFF_TB   17383424u
#define OFF_P1   17655296u   // BN partial s1 [32 b][2048 n] fp32
#define OFF_P2   17720832u   // BN partial s2 [32 b][2048 n] fp32
#define OFF_KS   17786368u   // ks fp32 [32 b][256]
#define OFF_VS   17794560u   // vs fp32 [32 b][256]
#define OFF_CNT  17802752u   // [32 nt] arrival counters, padded 32 uints (128B) apart
// end 17803776 slots ≈ 71.2 MB

typedef short bf16x8 __attribute__((ext_vector_type(8)));
typedef float f32x4  __attribute__((ext_vector_type(4)));

static __device__ inline unsigned short f2bf(float f) {
    __hip_bfloat16 h = __float2bfloat16(f);
    return *(unsigned short*)&h;
}
static __device__ inline float bf2f(unsigned short u) {
    unsigned v = ((unsigned)u) << 16;
    float f;
    __builtin_memcpy(&f, &v, 4);
    return f;
}

// Merged pack + ctx-GEMV + counter zeroing. Blocks 0..9: bf16 weight packing.
// Blocks 10..73: GEMV tiles (LDS-staged, coalesced). Block 74: zero counters.
__global__ __launch_bounds__(256) void kW(const float* __restrict__ Wl,
                                          const float* __restrict__ Wtc,
                                          const float* __restrict__ Wk,
                                          const float* __restrict__ Wv,
                                          const float* __restrict__ Wg,
                                          const float* __restrict__ Whb,
                                          const float* __restrict__ ctx,
                                          const float* __restrict__ bg,
                                          float* __restrict__ ws) {
    const unsigned bb = blockIdx.x, t = threadIdx.x;
    __shared__ float ctxs[32][260];
    __shared__ float wt[16][260];

    if (bb < 8u) {
        unsigned base = bb * 8192u;
        unsigned short* dst = (unsigned short*)(ws + OFF_WTCB);
#pragma unroll
        for (int j = 0; j < 32; j++) {
            unsigned i = base + (unsigned)j * 256u + t;
            dst[i] = f2bf(Wtc[i]);
        }
        return;
    } else if (bb == 8u) {
        unsigned short* dst = (unsigned short*)(ws + OFF_WLTB);   // [i][o]
        for (unsigned idx = t; idx < 32768u; idx += 256u) {
            unsigned i = idx >> 8, o = idx & 255u;
            dst[idx] = f2bf(Wl[o * 128u + i]);
        }
        return;
    } else if (bb == 9u) {
        unsigned short* dst = (unsigned short*)(ws + OFF_WLB);    // [o][i]
        for (unsigned idx = t; idx < 32768u; idx += 256u) dst[idx] = f2bf(Wl[idx]);
        return;
    } else if (bb == 74u) {
        unsigned* c = (unsigned*)(ws + OFF_CNT);
        for (unsigned i = t; i < 1024u; i += 256u) c[i] = 0u;
        return;
    }

    // ---- GEMV tile block ----
    const int j = bb - 10;            // 0..63
    const int m = j >> 4;             // matrix select
    const int o0 = (j & 15) * 16;
    const float* Wm; int C;
    if (m == 0)      { Wm = Wk;  C = 256; }
    else if (m == 1) { Wm = Wv;  C = 256; }
    else if (m == 2) { Wm = Wg;  C = DCTX; }
    else             { Wm = Whb; C = DCTX; }

    for (int i = t; i < 32 * 260; i += 256) {
        int b2 = i / 260, c = i - b2 * 260;
        ctxs[b2][c] = (c < DCTX) ? ctx[b2 * DCTX + c] : 0.f;
    }
    for (int i = t; i < 16 * C; i += 256) {
        int r = i / C, c = i - r * C;
        wt[r][c] = Wm[(size_t)(o0 + r) * C + c];
    }
    __syncthreads();

    const int ol = t & 15, b2 = t >> 4;       // each thread: 2 batches
    float s0 = 0.f, s1 = 0.f;
#pragma unroll 8
    for (int c = 0; c < C; c++) {
        float w = wt[ol][c];
        s0 += w * ctxs[b2][c];
        s1 += w * ctxs[b2 + 16][c];
    }
    const int o = o0 + ol;
    if (m == 0) {
        ws[OFF_KS + b2 * DOUT + o] = s0;
        ws[OFF_KS + (b2 + 16) * DOUT + o] = s1;
    } else if (m == 1) {
        ws[OFF_VS + b2 * DOUT + o] = s0;
        ws[OFF_VS + (b2 + 16) * DOUT + o] = s1;
    } else if (m == 2) {
        float bgo = bg[o];
        ws[OFF_G + b2 * DOUT + o] = 1.f / (1.f + __expf(-(s0 + bgo)));
        ws[OFF_G + (b2 + 16) * DOUT + o] = 1.f / (1.f + __expf(-(s1 + bgo)));
    } else {
        ws[OFF_HB + b2 * DOUT + o] = s0;
        ws[OFF_HB + (b2 + 16) * DOUT + o] = s1;
    }
}

// Softmax + A only. 1024 threads, grid B.
__global__ __launch_bounds__(1024) void kP(float* __restrict__ ws) {
    const int b = blockIdx.x, t = threadIdx.x;
    const int o = t & 255, q = t >> 8;
    __shared__ __align__(16) float ks[256], vs[256], rms[256], ris[256];
    __shared__ float pm[1024], ps[1024];
    if (t < 256)            ks[t] = ws[OFF_KS + b * DOUT + t];
    else if (t < 512)       vs[t - 256] = ws[OFF_VS + b * DOUT + (t - 256)];
    __syncthreads();

    const float ko = ks[o];
    const float4* vs4 = (const float4*)vs;
    float pmax = -1e30f;
#pragma unroll 4
    for (int j = q * 16; j < q * 16 + 16; j++) {
        float4 v = vs4[j];
        pmax = fmaxf(pmax, fmaxf(fmaxf(ko * v.x, ko * v.y), fmaxf(ko * v.z, ko * v.w)));
    }
    pm[q * 256 + o] = pmax;
    __syncthreads();
    float m = fmaxf(fmaxf(pm[o], pm[256 + o]), fmaxf(pm[512 + o], pm[768 + o]));
    float psum = 0.f;
#pragma unroll 4
    for (int j = q * 16; j < q * 16 + 16; j++) {
        float4 v = vs4[j];
        psum += __expf(ko * v.x - m) + __expf(ko * v.y - m)
              + __expf(ko * v.z - m) + __expf(ko * v.w - m);
    }
    ps[q * 256 + o] = psum;
    __syncthreads();
    float ri = 1.f / (ps[o] + ps[256 + o] + ps[512 + o] + ps[768 + o]);
    if (q == 0) { rms[o] = m; ris[o] = ri; }
    __syncthreads();

    const float ve = vs[o];
    float cp = 0.f;
#pragma unroll 4
    for (int o2 = q * 64; o2 < q * 64 + 64; o2++)
        cp += __expf(ks[o2] * ve - rms[o2]) * ris[o2];
    pm[q * 256 + o] = cp;
    __syncthreads();
    float ci = 1.f / (1e-9f + pm[o] + pm[256 + o] + pm[512 + o] + pm[768 + o]);
    unsigned short* Ab = (unsigned short*)(ws + OFF_AB) + (size_t)b * 65536u;
#pragma unroll 4
    for (int o2 = q * 64; o2 < q * 64 + 64; o2++) {
        float a = __expf(ks[o2] * ve - rms[o2]) * ris[o2] * ci;
        Ab[o2 * 256 + o] = f2bf(a);
    }
}

// Fused k4m+k5m, 64-row et-quarters. Mt in LDS (XOR-swizzled), then
// WM = Mt @ Wl^T and tb GEMV. grid (4 e-quarters, B), 512 threads.
__global__ __launch_bounds__(512) void k45(const float* __restrict__ bl,
                                           const float* __restrict__ btc,
                                           float* __restrict__ ws) {
    const int t = threadIdx.x, wid = t >> 6, l = t & 63;
    const int b = blockIdx.y, et = blockIdx.x;
    const int lrow = l & 15, lk = l >> 4;
    __shared__ unsigned short Mt[64 * 256];   // 32 KB, swizzled: col ^ ((row&7)<<3)
    const unsigned short* Wtcb = (const unsigned short*)(ws + OFF_WTCB);

    // ---- phase A: Mt rows [et*64, et*64+64), waves 2 rows x 4 cols ----
    {
        const unsigned short* Ab = (const unsigned short*)(ws + OFF_AB) + (size_t)b * 65536u;
        const int w_r = wid >> 2, w_c = wid & 3;
        const int rbase = et * 64 + w_r * 32;
        const int colbase = w_c * 64;
        f32x4 acc[2][4];
#pragma unroll
        for (int i = 0; i < 2; i++)
#pragma unroll
            for (int c = 0; c < 4; c++) acc[i][c] = (f32x4){0.f, 0.f, 0.f, 0.f};
        const unsigned short* ar0 = Wtcb + (rbase + lrow) * 256;
#pragma unroll
        for (int kk = 0; kk < 8; kk++) {
            int ko = kk * 32 + lk * 8;
            bf16x8 a0 = *(const bf16x8*)(ar0 + ko);
            bf16x8 a1 = *(const bf16x8*)(ar0 + 16 * 256 + ko);
            bf16x8 bfr[4];
#pragma unroll
            for (int c = 0; c < 4; c++)
                bfr[c] = *(const bf16x8*)(Ab + (colbase + c * 16 + lrow) * 256 + ko);
#pragma unroll
            for (int c = 0; c < 4; c++) {
                acc[0][c] = __builtin_amdgcn_mfma_f32_16x16x32_bf16(a0, bfr[c], acc[0][c], 0, 0, 0);
                acc[1][c] = __builtin_amdgcn_mfma_f32_16x16x32_bf16(a1, bfr[c], acc[1][c], 0, 0, 0);
            }
        }
#pragma unroll
        for (int t2 = 0; t2 < 2; t2++)
#pragma unroll
            for (int c = 0; c < 4; c++)
#pragma unroll
                for (int r = 0; r < 4; r++) {
                    int grow = rbase + t2 * 16 + lk * 4 + r;
                    int col = colbase + c * 16 + lrow;
                    float idv = bf2f(Wtcb[grow * 256 + col]);
                    int rl = grow - et * 64;
                    Mt[rl * 256 + (col ^ ((rl & 7) << 3))] = f2bf(idv - acc[t2][c][r]);
                }
    }
    __syncthreads();
    // ---- phase B: WM rows [et*64..+64) = Mt @ Wl^T ----
    {
        const unsigned short* Wltb = (const unsigned short*)(ws + OFF_WLTB);
        const int w_r = wid >> 2, w_c = wid & 3;
        const int rl0 = w_r * 32;
        const int colb = w_c * 32;
        f32x4 acc[2][2];
#pragma unroll
        for (int i = 0; i < 2; i++)
#pragma unroll
            for (int c = 0; c < 2; c++) acc[i][c] = (f32x4){0.f, 0.f, 0.f, 0.f};
        const int arow0 = rl0 + lrow, arow1 = rl0 + 16 + lrow;
        const int asw0 = (arow0 & 7) << 3, asw1 = (arow1 & 7) << 3;
#pragma unroll
        for (int kk = 0; kk < 8; kk++) {
            int ko = kk * 32 + lk * 8;
            bf16x8 a0 = *(const bf16x8*)(Mt + arow0 * 256 + (ko ^ asw0));
            bf16x8 a1 = *(const bf16x8*)(Mt + arow1 * 256 + (ko ^ asw1));
            bf16x8 bfr[2];
#pragma unroll
            for (int c = 0; c < 2; c++)
                bfr[c] = *(const bf16x8*)(Wltb + (colb + c * 16 + lrow) * 256 + ko);
#pragma unroll
            for (int c = 0; c < 2; c++) {
                acc[0][c] = __builtin_amdgcn_mfma_f32_16x16x32_bf16(a0, bfr[c], acc[0][c], 0, 0, 0);
                acc[1][c] = __builtin_amdgcn_mfma_f32_16x16x32_bf16(a1, bfr[c], acc[1][c], 0, 0, 0);
            }
        }
        unsigned short* WMBp = (unsigned short*)(ws + OFF_WMB) + (size_t)b * 32768u;
#pragma unroll
        for (int t2 = 0; t2 < 2; t2++)
#pragma unroll
            for (int c = 0; c < 2; c++)
#pragma unroll
                for (int r = 0; r < 4; r++) {
                    int row = et * 64 + rl0 + t2 * 16 + lk * 4 + r;
                    int col = colb + c * 16 + lrow;
                    WMBp[row * 128 + col] = f2bf(acc[t2][c][r]);
                }
    }
    // ---- tb bias GEMV from LDS Mt ----
    if (t < 64) {
        const int rl = t;
        const int sw = (rl & 7) << 3;
        float s = 0.f;
#pragma unroll 4
        for (int j = 0; j < 32; j++) {
            bf16x8 ch = *(const bf16x8*)(Mt + rl * 256 + ((j * 8) ^ sw));
#pragma unroll
            for (int u = 0; u < 8; u++) s += bl[j * 8 + u] * bf2f((unsigned short)ch[u]);
        }
        ws[OFF_TB + b * DOUT + et * 64 + rl] = s + btc[et * 64 + rl];
    }
}

#define LDP 136

// Fused kS+kF: ONE x staging, ONE tt GEMM. Stats partials + release arrive,
// x1 GEMM overlaps the wait, t0-only acquire spin on 128B-padded counter
// (R2-validated ordering recipe), fold L2-hot partials, epilogue from regs.
// grid (b fastest=32, nt=32): any 32 consecutive blocks = complete sibling
// group; ~768 co-resident blocks >> 32 -> forward progress guaranteed.
__global__ __launch_bounds__(256) void kFS(const float* __restrict__ x,
                                           const float* __restrict__ bl,
                                           const float* __restrict__ gamma,
                                           const float* __restrict__ beta,
                                           float* __restrict__ out,
                                           float* __restrict__ ws) {
    const int t = threadIdx.x;
    const int wid = t >> 6, l = t & 63;
    const int b = blockIdx.x;          // fastest dim
    const int nt = blockIdx.y;
    const int n0 = nt * 64;
    const int lrow = l & 15, lk = l >> 4;
    __shared__ unsigned short xs[64 * LDP];
    __shared__ float sp1[4][64], sp2[4][64];   // reused: stats phase, then fold
    __shared__ float scs[64], shs[64];

    // ---- stage x tile 64x128 fp32 -> bf16 LDS ----
    const float4* xg = (const float4*)(x + (size_t)(b * NN + n0) * DIN);
#pragma unroll
    for (int it = 0; it < 8; it++) {
        int idx = it * 256 + t;
        int row = idx >> 5, kq = idx & 31;
        float4 v = xg[idx];
        ushort4 u;
        u.x = f2bf(v.x); u.y = f2bf(v.y); u.z = f2bf(v.z); u.w = f2bf(v.w);
        *(ushort4*)(xs + row * LDP + kq * 4) = u;
    }
    __syncthreads();

    const int colbase = wid * 64;

    // ---- tt GEMM: acc = x @ WM^T + tb ----
    f32x4 acc[4][4];
#pragma unroll
    for (int rt = 0; rt < 4; rt++)
#pragma unroll
        for (int ct = 0; ct < 4; ct++) acc[rt][ct] = (f32x4){0.f, 0.f, 0.f, 0.f};
    {
        const unsigned short* wbM = (const unsigned short*)(ws + OFF_WMB) + (size_t)b * 32768u;
#pragma unroll
        for (int kk = 0; kk < 4; kk++) {
            int ko = kk * 32 + lk * 8;
            bf16x8 a[4];
#pragma unroll
            for (int rt = 0; rt < 4; rt++)
                a[rt] = *(const bf16x8*)(xs + (rt * 16 + lrow) * LDP + ko);
            bf16x8 bf[4];
#pragma unroll
            for (int ct = 0; ct < 4; ct++)
                bf[ct] = *(const bf16x8*)(wbM + (size_t)(colbase + ct * 16 + lrow) * DIN + ko);
#pragma unroll
            for (int rt = 0; rt < 4; rt++)
#pragma unroll
                for (int ct = 0; ct < 4; ct++)
                    acc[rt][ct] = __builtin_amdgcn_mfma_f32_16x16x32_bf16(a[rt], bf[ct], acc[rt][ct], 0, 0, 0);
        }
#pragma unroll
        for (int ct = 0; ct < 4; ct++) {
            float bv = ws[OFF_TB + b * DOUT + colbase + ct * 16 + lrow];
#pragma unroll
            for (int rt = 0; rt < 4; rt++)
#pragma unroll
                for (int r = 0; r < 4; r++) acc[rt][ct][r] += bv;
        }
    }

    // ---- per-n BN stats partials -> P1/P2, then release arrive ----
    {
        float s1[4][4], s2[4][4];
#pragma unroll
        for (int rt = 0; rt < 4; rt++)
#pragma unroll
            for (int r = 0; r < 4; r++) { s1[rt][r] = 0.f; s2[rt][r] = 0.f; }
#pragma unroll
        for (int rt = 0; rt < 4; rt++)
#pragma unroll
            for (int ct = 0; ct < 4; ct++)
#pragma unroll
                for (int r = 0; r < 4; r++) {
                    float v = acc[rt][ct][r];
                    s1[rt][r] += v; s2[rt][r] += v * v;
                }
#pragma unroll
        for (int off = 1; off < 16; off <<= 1) {
#pragma unroll
            for (int rt = 0; rt < 4; rt++)
#pragma unroll
                for (int r = 0; r < 4; r++) {
                    s1[rt][r] += __shfl_xor(s1[rt][r], off, 64);
                    s2[rt][r] += __shfl_xor(s2[rt][r], off, 64);
                }
        }
        if (lrow == 0) {
#pragma unroll
            for (int rt = 0; rt < 4; rt++)
#pragma unroll
                for (int r = 0; r < 4; r++) {
                    int nidx = rt * 16 + lk * 4 + r;
                    sp1[wid][nidx] = s1[rt][r];
                    sp2[wid][nidx] = s2[rt][r];
                }
        }
    }
    __syncthreads();
    if (t < 64) {
        float S1 = sp1[0][t] + sp1[1][t] + sp1[2][t] + sp1[3][t];
        float S2 = sp2[0][t] + sp2[1][t] + sp2[2][t] + sp2[3][t];
        ws[OFF_P1 + (size_t)b * NN + n0 + t] = S1;
        ws[OFF_P2 + (size_t)b * NN + n0 + t] = S2;
    }
    __syncthreads();   // all partial stores drained (vmcnt(0) at barrier)

    unsigned* cnt = (unsigned*)(ws + OFF_CNT) + (size_t)nt * 32;   // 128B-padded
    if (t == 0)
        __hip_atomic_fetch_add(cnt, 1u, __ATOMIC_RELEASE, __HIP_MEMORY_SCOPE_AGENT);

    // ---- x1 GEMM (overlaps siblings' arrival): acc0 = x @ Wl^T + bl ----
    f32x4 acc0[4][4];
#pragma unroll
    for (int rt = 0; rt < 4; rt++)
#pragma unroll
        for (int ct = 0; ct < 4; ct++) acc0[rt][ct] = (f32x4){0.f, 0.f, 0.f, 0.f};
    {
        const unsigned short* wbL = (const unsigned short*)(ws + OFF_WLB);
#pragma unroll
        for (int kk = 0; kk < 4; kk++) {
            int ko = kk * 32 + lk * 8;
            bf16x8 a[4];
#pragma unroll
            for (int rt = 0; rt < 4; rt++)
                a[rt] = *(const bf16x8*)(xs + (rt * 16 + lrow) * LDP + ko);
            bf16x8 bf[4];
#pragma unroll
            for (int ct = 0; ct < 4; ct++)
                bf[ct] = *(const bf16x8*)(wbL + (size_t)(colbase + ct * 16 + lrow) * DIN + ko);
#pragma unroll
            for (int rt = 0; rt < 4; rt++)
#pragma unroll
                for (int ct = 0; ct < 4; ct++)
                    acc0[rt][ct] = __builtin_amdgcn_mfma_f32_16x16x32_bf16(a[rt], bf[ct], acc0[rt][ct], 0, 0, 0);
        }
#pragma unroll
        for (int ct = 0; ct < 4; ct++) {
            float bv = bl[colbase + ct * 16 + lrow];
#pragma unroll
            for (int rt = 0; rt < 4; rt++)
#pragma unroll
                for (int r = 0; r < 4; r++) acc0[rt][ct][r] += bv;
        }
    }

    // ---- t0-only acquire spin, then fold L2-hot partials ----
    if (t == 0) {
        while (__hip_atomic_load(cnt, __ATOMIC_ACQUIRE, __HIP_MEMORY_SCOPE_AGENT) < (unsigned)BB)
            __builtin_amdgcn_s_sleep(32);
    }
    __syncthreads();

    {
        int n = t & 63, g = t >> 6;          // 4 groups x 8 batches
        float S1 = 0.f, S2 = 0.f;
#pragma unroll
        for (int b2 = g * 8; b2 < g * 8 + 8; b2++) {
            S1 += ws[OFF_P1 + (size_t)b2 * NN + n0 + n];
            S2 += ws[OFF_P2 + (size_t)b2 * NN + n0 + n];
        }
        sp1[g][n] = S1; sp2[g][n] = S2;
    }
    __syncthreads();
    if (t < 64) {
        float S1 = sp1[0][t] + sp1[1][t] + sp1[2][t] + sp1[3][t];
        float S2 = sp2[0][t] + sp2[1][t] + sp2[2][t] + sp2[3][t];
        float mean = S1 * (1.f / 8192.f);
        float var  = S2 * (1.f / 8192.f) - mean * mean;
        float sc = gamma[n0 + t] * rsqrtf(fmaxf(var, 0.f) + 1e-5f);
        scs[t] = sc;
        shs[t] = beta[n0 + t] - mean * sc;
    }
    __syncthreads();

    // ---- epilogue straight from registers: out = (x1 + relu(bn(tt)))*g + hb ----
    float gv[4], hbv[4];
#pragma unroll
    for (int ct = 0; ct < 4; ct++) {
        int o = colbase + ct * 16 + lrow;
        gv[ct]  = ws[OFF_G  + b * DOUT + o];
        hbv[ct] = ws[OFF_HB + b * DOUT + o];
    }
#pragma unroll
    for (int rt = 0; rt < 4; rt++)
#pragma unroll
        for (int r = 0; r < 4; r++) {
            int nidx = rt * 16 + lk * 4 + r;
            float sc = scs[nidx], sh = shs[nidx];
            int n = n0 + nidx;
#pragma unroll
            for (int ct = 0; ct < 4; ct++) {
                int o = colbase + ct * 16 + lrow;
                float rv = fmaxf(acc[rt][ct][r] * sc + sh, 0.f);
                out[(size_t)((b * NN + n) * DOUT) + o] = (acc0[rt][ct][r] + rv) * gv[ct] + hbv[ct];
            }
        }
}

extern "C" void kernel_launch(void* const* d_in, const int* in_sizes, int n_in,
                              void* d_out, int out_size, void* d_ws, size_t ws_size,
                              hipStream_t stream) {
    const float* ctx   = (const float*)d_in[0];
    const float* x     = (const float*)d_in[1];
    const float* Wl    = (const float*)d_in[2];
    const float* bl    = (const float*)d_in[3];
    const float* Whb   = (const float*)d_in[4];
    const float* Wg    = (const float*)d_in[5];
    const float* bg    = (const float*)d_in[6];
    const float* Wk    = (const float*)d_in[7];
    const float* Wv    = (const float*)d_in[8];
    const float* Wtc   = (const float*)d_in[9];
    const float* btc   = (const float*)d_in[10];
    const float* gamma = (const float*)d_in[11];
    const float* beta  = (const float*)d_in[12];
    float* out = (float*)d_out;
    float* ws  = (float*)d_ws;

    kW  <<<75, 256, 0, stream>>>(Wl, Wtc, Wk, Wv, Wg, Whb, ctx, bg, ws);
    kP  <<<BB, 1024, 0, stream>>>(ws);
    k45 <<<dim3(4, BB), 512, 0, stream>>>(bl, btc, ws);
    kFS <<<dim3(BB, 32), 256, 0, stream>>>(x, bl, gamma, beta, out, ws);
}